// Round 1
// baseline (2435.356 us; speedup 1.0000x reference)
//
#include <hip/hip_runtime.h>

#define NB 64
#define NN 512
#define NL 12
#define ND 128
#define NZ 384
#define NCONV 3
#define BN_EPS 1e-3f

// v[b,n,d] = node_w[node_types[b,n]] * mask + slot_types
__global__ __launch_bounds__(256) void embed_kernel(
    const int* __restrict__ node_types,
    const float* __restrict__ slot_types,
    const float* __restrict__ node_w,
    float* __restrict__ v)
{
    int i = blockIdx.x * 256 + threadIdx.x;   // over NB*NN*ND, exact
    int bn = i >> 7;
    int d = i & 127;
    int t = node_types[bn];
    float m = t >= 0 ? 1.f : 0.f;
    int idx = t >= 0 ? t : 0;
    v[i] = node_w[idx * ND + d] * m + slot_types[i];
}

// One block per (b,n) node. threadIdx.x = output channel d (0..127).
__global__ __launch_bounds__(128) void conv_kernel(
    const float* __restrict__ v_in,
    float* __restrict__ v_out,
    const int* __restrict__ neighbor_list,
    const int* __restrict__ edge_types,
    const float* __restrict__ edge_w,
    const float* __restrict__ wf,   // (NZ, ND), pre-offset for this conv
    const float* __restrict__ bf,   // (ND)
    const float* __restrict__ ws,
    const float* __restrict__ bs,
    const float* __restrict__ bn_gamma,
    const float* __restrict__ bn_beta,
    const float* __restrict__ bn_mean,
    const float* __restrict__ bn_var)
{
    __shared__ float s_self[ND];
    __shared__ float s_nb[ND][16];   // [z][l], padded 12->16 for b128 reads
    __shared__ float s_e[ND][16];
    __shared__ float s_mask[NL];
    __shared__ int   s_allok[2];

    const int bn = blockIdx.x;
    const int b  = bn >> 9;          // NN = 512
    const int d  = threadIdx.x;

    // ---- stage self row, neighbor rows, edge rows into LDS ----
    s_self[d] = v_in[(size_t)bn * ND + d];
    const int* nl = neighbor_list + (size_t)bn * NL;
    const int* et = edge_types   + (size_t)bn * NL;
    #pragma unroll
    for (int l = 0; l < NL; ++l) {
        int nli = nl[l];
        float m = nli >= 0 ? 1.f : 0.f;
        int ns  = nli >= 0 ? nli : 0;
        s_nb[d][l] = v_in[((size_t)b * NN + ns) * ND + d] * m;
        int ei = et[l];
        float em = ei >= 0 ? 1.f : 0.f;
        int es   = ei >= 0 ? ei : 0;
        s_e[d][l] = edge_w[(size_t)es * ND + d] * em;
        if (d == 0) s_mask[l] = m;
    }
    __syncthreads();

    // ---- self contribution (z in [0,128)): identical for all l ----
    float self_f = 0.f, self_s = 0.f;
    for (int z = 0; z < ND; ++z) {
        float vz = s_self[z];
        self_f = fmaf(vz, wf[z * ND + d], self_f);
        self_s = fmaf(vz, ws[z * ND + d], self_s);
    }

    float accf[NL], accs[NL];
    #pragma unroll
    for (int l = 0; l < NL; ++l) { accf[l] = 0.f; accs[l] = 0.f; }

    // ---- neighbor contribution (z in [128,256)) ----
    for (int z = 0; z < ND; ++z) {
        float wfv = wf[(ND + z) * ND + d];
        float wsv = ws[(ND + z) * ND + d];
        float4 a0 = *(const float4*)&s_nb[z][0];
        float4 a1 = *(const float4*)&s_nb[z][4];
        float4 a2 = *(const float4*)&s_nb[z][8];
        const float av[NL] = {a0.x,a0.y,a0.z,a0.w, a1.x,a1.y,a1.z,a1.w, a2.x,a2.y,a2.z,a2.w};
        #pragma unroll
        for (int l = 0; l < NL; ++l) {
            accf[l] = fmaf(av[l], wfv, accf[l]);
            accs[l] = fmaf(av[l], wsv, accs[l]);
        }
    }

    // ---- edge contribution (z in [256,384)) ----
    for (int z = 0; z < ND; ++z) {
        float wfv = wf[(2 * ND + z) * ND + d];
        float wsv = ws[(2 * ND + z) * ND + d];
        float4 a0 = *(const float4*)&s_e[z][0];
        float4 a1 = *(const float4*)&s_e[z][4];
        float4 a2 = *(const float4*)&s_e[z][8];
        const float av[NL] = {a0.x,a0.y,a0.z,a0.w, a1.x,a1.y,a1.z,a1.w, a2.x,a2.y,a2.z,a2.w};
        #pragma unroll
        for (int l = 0; l < NL; ++l) {
            accf[l] = fmaf(av[l], wfv, accf[l]);
            accs[l] = fmaf(av[l], wsv, accs[l]);
        }
    }

    // ---- activations, neighbor-sum, masked BN ----
    const float bfd = bf[d], bsd = bs[d];
    float ssum = 0.f;
    #pragma unroll
    for (int l = 0; l < NL; ++l) {
        float pf = self_f + accf[l] + bfd;
        float ps = self_s + accs[l] + bsd;
        float sig = 1.f / (1.f + expf(-pf));
        float th  = tanhf(ps);
        ssum += sig * th * s_mask[l];
    }
    float x = s_self[d] + ssum;

    bool ok = fabsf(x) > 1e-5f;
    int wall = __all(ok);
    if ((threadIdx.x & 63) == 0) s_allok[threadIdx.x >> 6] = wall;
    __syncthreads();
    bool valid = s_allok[0] && s_allok[1];

    float g  = bn_gamma[d], be = bn_beta[d], mu = bn_mean[d], va = bn_var[d];
    float bnv = g * (x - mu) * (1.f / sqrtf(va + BN_EPS)) + be;
    v_out[(size_t)bn * ND + d] = valid ? bnv : 0.f;
}

// masked mean over nodes + final dense (D -> 1)
__global__ __launch_bounds__(128) void pool_kernel(
    const float* __restrict__ v,
    const int* __restrict__ node_types,
    const float* __restrict__ dense_w,
    const float* __restrict__ dense_b,
    float* __restrict__ out)
{
    __shared__ float s_part[2];
    const int b = blockIdx.x;
    const int d = threadIdx.x;
    float sum = 0.f, cnt = 0.f;
    for (int n = 0; n < NN; ++n) {
        int t = node_types[b * NN + n];
        float m = t >= 0 ? 1.f : 0.f;
        sum += v[((size_t)b * NN + n) * ND + d] * m;
        cnt += m;
    }
    float p = (sum / cnt) * dense_w[d];
    #pragma unroll
    for (int off = 32; off > 0; off >>= 1) p += __shfl_down(p, off);
    if ((threadIdx.x & 63) == 0) s_part[threadIdx.x >> 6] = p;
    __syncthreads();
    if (threadIdx.x == 0) out[b] = s_part[0] + s_part[1] + dense_b[0];
}

extern "C" void kernel_launch(void* const* d_in, const int* in_sizes, int n_in,
                              void* d_out, int out_size, void* d_ws, size_t ws_size,
                              hipStream_t stream) {
    const int*   node_types    = (const int*)d_in[0];
    const int*   neighbor_list = (const int*)d_in[1];
    const int*   edge_types    = (const int*)d_in[2];
    const float* slot_types    = (const float*)d_in[3];
    const float* node_w        = (const float*)d_in[4];
    const float* edge_w        = (const float*)d_in[5];
    const float* wf            = (const float*)d_in[6];
    const float* bf            = (const float*)d_in[7];
    const float* wsig          = (const float*)d_in[8];
    const float* bs            = (const float*)d_in[9];
    const float* bn_gamma      = (const float*)d_in[10];
    const float* bn_beta       = (const float*)d_in[11];
    const float* bn_mean       = (const float*)d_in[12];
    const float* bn_var        = (const float*)d_in[13];
    const float* dense_w       = (const float*)d_in[14];
    const float* dense_b       = (const float*)d_in[15];
    float* out = (float*)d_out;

    float* vA = (float*)d_ws;
    float* vB = vA + (size_t)NB * NN * ND;

    embed_kernel<<<(NB * NN * ND) / 256, 256, 0, stream>>>(node_types, slot_types, node_w, vA);

    const float* cin = vA;
    float* cout = vB;
    for (int i = 0; i < NCONV; ++i) {
        conv_kernel<<<NB * NN, 128, 0, stream>>>(
            cin, cout, neighbor_list, edge_types, edge_w,
            wf + (size_t)i * NZ * ND, bf + i * ND,
            wsig + (size_t)i * NZ * ND, bs + i * ND,
            bn_gamma + i * ND, bn_beta + i * ND, bn_mean + i * ND, bn_var + i * ND);
        float* t = (float*)cin; cin = cout; cout = t;
    }

    pool_kernel<<<NB, 128, 0, stream>>>(cin, node_types, dense_w, dense_b, out);
}

// Round 2
// 1308.082 us; speedup vs baseline: 1.8618x; 1.8618x over previous
//
#include <hip/hip_runtime.h>

#define NB 64
#define NN 512
#define NL 12
#define ND 128
#define NZ 384
#define NCONV 3
#define BN_EPS 1e-3f
#define LO_SCALE 2048.0f
#define INV_LO (1.0f/2048.0f)

using half8  = __attribute__((ext_vector_type(8))) _Float16;
using floatx4 = __attribute__((ext_vector_type(4))) float;
typedef _Float16 f16;

__device__ __forceinline__ floatx4 mfma16(half8 a, half8 b, floatx4 c) {
    return __builtin_amdgcn_mfma_f32_16x16x32_f16(a, b, c, 0, 0, 0);
}

// split x0,x1 into f16 hi pair (returned) and scaled-lo pair (out param)
__device__ __forceinline__ unsigned pack2(float x0, float x1, unsigned& lo2) {
    f16 h0 = (f16)x0, h1 = (f16)x1;
    f16 l0 = (f16)((x0 - (float)h0) * LO_SCALE);
    f16 l1 = (f16)((x1 - (float)h1) * LO_SCALE);
    union { f16 h[2]; unsigned u; } a, b;
    a.h[0] = h0; a.h[1] = h1; b.h[0] = l0; b.h[1] = l1;
    lo2 = b.u;
    return a.u;
}

// ---------------- weight prep: transpose + f16 hi/lo split ----------------
// WmT[c][n][k] (n-major, K=256): k -> z=128+k ; n<128 -> wf, else ws col n-128
// WsT[c][n][k] (K=128): k -> z=k
__global__ __launch_bounds__(256) void prep_kernel(
    const float* __restrict__ wf, const float* __restrict__ wsg,
    f16* __restrict__ WmT_hi, f16* __restrict__ WmT_lo,
    f16* __restrict__ WsT_hi, f16* __restrict__ WsT_lo)
{
    int id = blockIdx.x * 256 + threadIdx.x;   // total 294912
    if (id < 3 * 65536) {
        int c = id >> 16, rem = id & 65535;
        int n = rem >> 8, k = rem & 255;
        int z = 128 + k;
        float w = (n < 128) ? wf[((size_t)c * NZ + z) * ND + n]
                            : wsg[((size_t)c * NZ + z) * ND + (n - 128)];
        f16 hi = (f16)w;
        f16 lo = (f16)((w - (float)hi) * LO_SCALE);
        WmT_hi[id] = hi; WmT_lo[id] = lo;
    } else {
        int id2 = id - 3 * 65536;              // < 3*32768
        int c = id2 >> 15, rem = id2 & 32767;
        int n = rem >> 7, k = rem & 127;
        float w = (n < 128) ? wf[((size_t)c * NZ + k) * ND + n]
                            : wsg[((size_t)c * NZ + k) * ND + (n - 128)];
        f16 hi = (f16)w;
        f16 lo = (f16)((w - (float)hi) * LO_SCALE);
        WsT_hi[id2] = hi; WsT_lo[id2] = lo;
    }
}

// ---------------- embed ----------------
__global__ __launch_bounds__(256) void embed_kernel(
    const int* __restrict__ node_types,
    const float* __restrict__ slot_types,
    const float* __restrict__ node_w,
    float* __restrict__ v)
{
    int i = blockIdx.x * 256 + threadIdx.x;
    int bn = i >> 7, d = i & 127;
    int t = node_types[bn];
    float m = t >= 0 ? 1.f : 0.f;
    int idx = t >= 0 ? t : 0;
    v[i] = node_w[idx * ND + d] * m + slot_types[i];
}

// ---------------- self GEMM: selfacc[node][256] = v . Wself + bias ----------------
__global__ __launch_bounds__(256) void self_gemm_kernel(
    const float* __restrict__ v_in,
    const f16* __restrict__ WsT_hi, const f16* __restrict__ WsT_lo,
    const float* __restrict__ bfv, const float* __restrict__ bsv,
    float* __restrict__ selfacc)
{
    __shared__ __align__(16) char sA[16384];   // hi: 32x128 f16 @0, lo @8192
    const int node0 = blockIdx.x * 32;
    const int t = threadIdx.x;
    #pragma unroll
    for (int s = 0; s < 8; ++s) {
        int i = s * 256 + t;
        int r = i >> 6, d2 = (i & 63) << 1;
        int xr = (r & 7) << 4;
        const float* vp = v_in + ((size_t)(node0 + r)) * ND + d2;
        unsigned lo2, hi2 = pack2(vp[0], vp[1], lo2);
        int byte0 = r * 256 + d2 * 2;
        *(unsigned*)(sA + (byte0 ^ xr)) = hi2;
        *(unsigned*)(sA + 8192 + (byte0 ^ xr)) = lo2;
    }
    __syncthreads();
    const int lane = t & 63, wave = t >> 6;
    const int l15 = lane & 15, l4 = lane >> 4;
    floatx4 acc0[2][4] = {}, acc1[2][4] = {};
    int abase[2], axr[2];
    #pragma unroll
    for (int mt = 0; mt < 2; ++mt) {
        int row = mt * 16 + l15;
        axr[mt] = (row & 7) << 4;
        abase[mt] = row * 256 + l4 * 16;
    }
    const f16* bph[4]; const f16* bpl[4];
    #pragma unroll
    for (int nt = 0; nt < 4; ++nt) {
        int col = wave * 64 + nt * 16 + l15;
        bph[nt] = WsT_hi + col * 128 + l4 * 8;
        bpl[nt] = WsT_lo + col * 128 + l4 * 8;
    }
    #pragma unroll
    for (int ks = 0; ks < 4; ++ks) {
        const int kb = ks * 64;
        half8 ah[2], al[2], bh[4], bl[4];
        #pragma unroll
        for (int mt = 0; mt < 2; ++mt) {
            ah[mt] = *(const half8*)(sA + ((abase[mt] + kb) ^ axr[mt]));
            al[mt] = *(const half8*)(sA + 8192 + ((abase[mt] + kb) ^ axr[mt]));
        }
        #pragma unroll
        for (int nt = 0; nt < 4; ++nt) {
            bh[nt] = *(const half8*)(bph[nt] + ks * 32);
            bl[nt] = *(const half8*)(bpl[nt] + ks * 32);
        }
        #pragma unroll
        for (int mt = 0; mt < 2; ++mt)
        #pragma unroll
        for (int nt = 0; nt < 4; ++nt) {
            acc0[mt][nt] = mfma16(ah[mt], bh[nt], acc0[mt][nt]);
            acc1[mt][nt] = mfma16(ah[mt], bl[nt], acc1[mt][nt]);
            acc1[mt][nt] = mfma16(al[mt], bh[nt], acc1[mt][nt]);
        }
    }
    float biasv[4];
    #pragma unroll
    for (int nt = 0; nt < 4; ++nt) {
        int col = wave * 64 + nt * 16 + l15;
        biasv[nt] = (col < 128) ? bfv[col] : bsv[col - 128];
    }
    #pragma unroll
    for (int mt = 0; mt < 2; ++mt)
    #pragma unroll
    for (int nt = 0; nt < 4; ++nt)
    #pragma unroll
    for (int r = 0; r < 4; ++r) {
        int row = mt * 16 + l4 * 4 + r;
        int col = wave * 64 + nt * 16 + l15;
        selfacc[(size_t)(node0 + row) * 256 + col] =
            acc0[mt][nt][r] + acc1[mt][nt][r] * INV_LO + biasv[nt];
    }
}

// ---------------- main conv: 4 nodes (48 rows) x 256 cols per block ----------------
__global__ __launch_bounds__(256) void conv_mfma_kernel(
    const float* __restrict__ v_in, float* __restrict__ v_out,
    const int* __restrict__ neighbor_list, const int* __restrict__ edge_types,
    const float* __restrict__ edge_w,
    const f16* __restrict__ WmT_hi, const f16* __restrict__ WmT_lo,
    const float* __restrict__ selfacc,
    const float* __restrict__ bn_gamma, const float* __restrict__ bn_beta,
    const float* __restrict__ bn_mean, const float* __restrict__ bn_var)
{
    __shared__ __align__(16) char sA[49152];   // A_hi 48x256 f16 @0, A_lo @24576; reused as p[48][256] f32
    __shared__ float s_mask[48];
    __shared__ int s_nbr[48], s_eid[48];
    __shared__ int s_flags[4][2];

    const int node0 = blockIdx.x * 4;
    const int bb = node0 >> 9;                 // batch (NN=512)
    const int t = threadIdx.x;

    if (t < 48) {
        int node = node0 + (t / 12);
        int l = t % 12;
        int nl = neighbor_list[node * NL + l];
        s_nbr[t] = nl;
        s_mask[t] = (nl >= 0) ? 1.f : 0.f;
        s_eid[t] = edge_types[node * NL + l];
    }
    __syncthreads();

    // ---- stage A: rows (node,l); k<128 = neighbor v, k>=128 = edge embed ----
    #pragma unroll
    for (int s = 0; s < 12; ++s) {
        int i = s * 256 + t;
        int r = i >> 6, d2 = (i & 63) << 1;
        int xr = (r & 7) << 4;
        int nb = s_nbr[r];
        float x0 = 0.f, x1 = 0.f;
        if (nb >= 0) {
            const float* vp = v_in + ((size_t)(bb * NN + nb)) * ND + d2;
            x0 = vp[0]; x1 = vp[1];
        }
        unsigned lo2, hi2 = pack2(x0, x1, lo2);
        int byte0 = r * 512 + d2 * 2;
        *(unsigned*)(sA + (byte0 ^ xr)) = hi2;
        *(unsigned*)(sA + 24576 + (byte0 ^ xr)) = lo2;

        int ei = s_eid[r];
        float y0 = 0.f, y1 = 0.f;
        if (ei >= 0) {
            const float* ep = edge_w + (size_t)ei * ND + d2;
            y0 = ep[0]; y1 = ep[1];
        }
        unsigned elo2, ehi2 = pack2(y0, y1, elo2);
        int byte1 = r * 512 + 256 + d2 * 2;
        *(unsigned*)(sA + (byte1 ^ xr)) = ehi2;
        *(unsigned*)(sA + 24576 + (byte1 ^ xr)) = elo2;
    }
    __syncthreads();

    const int lane = t & 63, wave = t >> 6;
    const int l15 = lane & 15, l4 = lane >> 4;

    floatx4 acc0[3][4] = {}, acc1[3][4] = {};
    int abase[3], axr[3];
    #pragma unroll
    for (int mt = 0; mt < 3; ++mt) {
        int row = mt * 16 + l15;
        axr[mt] = (row & 7) << 4;
        abase[mt] = row * 512 + l4 * 16;
    }
    const f16* bph[4]; const f16* bpl[4];
    #pragma unroll
    for (int nt = 0; nt < 4; ++nt) {
        int col = wave * 64 + nt * 16 + l15;
        bph[nt] = WmT_hi + col * 256 + l4 * 8;
        bpl[nt] = WmT_lo + col * 256 + l4 * 8;
    }
    #pragma unroll
    for (int ks = 0; ks < 8; ++ks) {
        const int kb = ks * 64;
        half8 ah[3], al[3], bh[4], bl[4];
        #pragma unroll
        for (int mt = 0; mt < 3; ++mt) {
            ah[mt] = *(const half8*)(sA + ((abase[mt] + kb) ^ axr[mt]));
            al[mt] = *(const half8*)(sA + 24576 + ((abase[mt] + kb) ^ axr[mt]));
        }
        #pragma unroll
        for (int nt = 0; nt < 4; ++nt) {
            bh[nt] = *(const half8*)(bph[nt] + ks * 32);
            bl[nt] = *(const half8*)(bpl[nt] + ks * 32);
        }
        #pragma unroll
        for (int mt = 0; mt < 3; ++mt)
        #pragma unroll
        for (int nt = 0; nt < 4; ++nt) {
            acc0[mt][nt] = mfma16(ah[mt], bh[nt], acc0[mt][nt]);
            acc1[mt][nt] = mfma16(ah[mt], bl[nt], acc1[mt][nt]);
            acc1[mt][nt] = mfma16(al[mt], bh[nt], acc1[mt][nt]);
        }
    }
    __syncthreads();

    // ---- write pre-activations to LDS (reuse A region) ----
    float* p = (float*)sA;                     // p[48][256]
    #pragma unroll
    for (int mt = 0; mt < 3; ++mt)
    #pragma unroll
    for (int nt = 0; nt < 4; ++nt)
    #pragma unroll
    for (int r = 0; r < 4; ++r) {
        int row = mt * 16 + l4 * 4 + r;
        int col = wave * 64 + nt * 16 + l15;
        p[row * 256 + col] = acc0[mt][nt][r] + acc1[mt][nt][r] * INV_LO;
    }
    __syncthreads();

    // ---- epilogue: activations, l-sum, BN + validity ----
    const int d = t & 127, gh = t >> 7;
    const float g_ = bn_gamma[d], be = bn_beta[d], mu = bn_mean[d];
    const float rsv = 1.f / sqrtf(bn_var[d] + BN_EPS);
    #pragma unroll
    for (int it = 0; it < 2; ++it) {
        int gg = gh * 2 + it;
        int node = node0 + gg;
        float pfb = selfacc[(size_t)node * 256 + d];
        float psb = selfacc[(size_t)node * 256 + 128 + d];
        float ssum = 0.f;
        #pragma unroll
        for (int l = 0; l < 12; ++l) {
            int r = gg * 12 + l;
            float pf = p[r * 256 + d] + pfb;
            float ps = p[r * 256 + 128 + d] + psb;
            float sig = 1.f / (1.f + expf(-pf));
            float th = tanhf(ps);
            ssum += sig * th * s_mask[r];
        }
        float x = v_in[(size_t)node * ND + d] + ssum;
        int ok = __all(fabsf(x) > 1e-5f);
        if (lane == 0) s_flags[gg][wave & 1] = ok;
        __syncthreads();
        int valid = s_flags[gg][0] && s_flags[gg][1];
        float bnv = g_ * (x - mu) * rsv + be;
        v_out[(size_t)node * ND + d] = valid ? bnv : 0.f;
    }
}

// ---------------- pool ----------------
__global__ __launch_bounds__(128) void pool_kernel(
    const float* __restrict__ v,
    const int* __restrict__ node_types,
    const float* __restrict__ dense_w,
    const float* __restrict__ dense_b,
    float* __restrict__ out)
{
    __shared__ float s_part[2];
    const int b = blockIdx.x;
    const int d = threadIdx.x;
    float sum = 0.f, cnt = 0.f;
    for (int n = 0; n < NN; ++n) {
        int t = node_types[b * NN + n];
        float m = t >= 0 ? 1.f : 0.f;
        sum += v[((size_t)b * NN + n) * ND + d] * m;
        cnt += m;
    }
    float pv = (sum / cnt) * dense_w[d];
    #pragma unroll
    for (int off = 32; off > 0; off >>= 1) pv += __shfl_down(pv, off);
    if ((threadIdx.x & 63) == 0) s_part[threadIdx.x >> 6] = pv;
    __syncthreads();
    if (threadIdx.x == 0) out[b] = s_part[0] + s_part[1] + dense_b[0];
}

extern "C" void kernel_launch(void* const* d_in, const int* in_sizes, int n_in,
                              void* d_out, int out_size, void* d_ws, size_t ws_size,
                              hipStream_t stream) {
    const int*   node_types    = (const int*)d_in[0];
    const int*   neighbor_list = (const int*)d_in[1];
    const int*   edge_types    = (const int*)d_in[2];
    const float* slot_types    = (const float*)d_in[3];
    const float* node_w        = (const float*)d_in[4];
    const float* edge_w        = (const float*)d_in[5];
    const float* wf            = (const float*)d_in[6];
    const float* bfv           = (const float*)d_in[7];
    const float* wsg           = (const float*)d_in[8];
    const float* bsv           = (const float*)d_in[9];
    const float* bn_gamma      = (const float*)d_in[10];
    const float* bn_beta       = (const float*)d_in[11];
    const float* bn_mean       = (const float*)d_in[12];
    const float* bn_var        = (const float*)d_in[13];
    const float* dense_w       = (const float*)d_in[14];
    const float* dense_b       = (const float*)d_in[15];
    float* out = (float*)d_out;

    const size_t NV = (size_t)NB * NN * ND;    // 4,194,304
    float* wsf = (float*)d_ws;
    float* vA      = wsf;
    float* vB      = wsf + NV;
    float* selfacc = wsf + 2 * NV;             // 2*NV floats
    f16* WmT_hi = (f16*)(wsf + 4 * NV);
    f16* WmT_lo = WmT_hi + 3 * 65536;
    f16* WsT_hi = WmT_lo + 3 * 65536;
    f16* WsT_lo = WsT_hi + 3 * 32768;

    prep_kernel<<<1152, 256, 0, stream>>>(wf, wsg, WmT_hi, WmT_lo, WsT_hi, WsT_lo);
    embed_kernel<<<(NB * NN * ND) / 256, 256, 0, stream>>>(node_types, slot_types, node_w, vA);

    const float* cin = vA;
    float* cout = vB;
    for (int c = 0; c < NCONV; ++c) {
        self_gemm_kernel<<<(NB * NN) / 32, 256, 0, stream>>>(
            cin, WsT_hi + c * 32768, WsT_lo + c * 32768,
            bfv + c * ND, bsv + c * ND, selfacc);
        conv_mfma_kernel<<<(NB * NN) / 4, 256, 0, stream>>>(
            cin, cout, neighbor_list, edge_types, edge_w,
            WmT_hi + c * 65536, WmT_lo + c * 65536, selfacc,
            bn_gamma + c * ND, bn_beta + c * ND, bn_mean + c * ND, bn_var + c * ND);
        float* tmp = (float*)cin; cin = cout; cout = tmp;
    }

    pool_kernel<<<NB, 128, 0, stream>>>(cin, node_types, dense_w, dense_b, out);
}

// Round 3
// 1017.230 us; speedup vs baseline: 2.3941x; 1.2859x over previous
//
#include <hip/hip_runtime.h>

#define NB 64
#define NN 512
#define NL 12
#define ND 128
#define NZ 384
#define NCONV 3
#define VOCAB 1000
#define BN_EPS 1e-3f
#define LO_SCALE 2048.0f
#define INV_LO (1.0f/2048.0f)

typedef _Float16 f16;
using half8 = __attribute__((ext_vector_type(8))) _Float16;
using floatx16 = __attribute__((ext_vector_type(16))) float;

__device__ __forceinline__ floatx16 mfma32(half8 a, half8 b, floatx16 c) {
    return __builtin_amdgcn_mfma_f32_32x32x16_f16(a, b, c, 0, 0, 0);
}
__device__ __forceinline__ float fast_sigmoid(float x) {
    return __builtin_amdgcn_rcpf(1.f + __expf(-x));
}
__device__ __forceinline__ float fast_tanh(float x) {
    // robust for +-inf pre-activations: (e=inf)->1, (e=0)->-1
    return 1.f - 2.f * __builtin_amdgcn_rcpf(__expf(2.f * x) + 1.f);
}
__device__ __forceinline__ void split1(float x, f16& h, f16& l) {
    h = (f16)x; l = (f16)((x - (float)h) * LO_SCALE);
}

// ---- weight prep: transpose + f16 hi/lo split ----
// WmT[c][col][k], k -> z=128+k (neighbor part). WsT[c][col][k], k -> z=k (self part).
// col<128 -> wf column, col>=128 -> ws column col-128.
__global__ __launch_bounds__(256) void prep_kernel(
    const float* __restrict__ wf, const float* __restrict__ wsg,
    f16* __restrict__ WmT_hi, f16* __restrict__ WmT_lo,
    f16* __restrict__ WsT_hi, f16* __restrict__ WsT_lo)
{
    int id = blockIdx.x * 256 + threadIdx.x;   // 196608 total
    int hlf = id / 98304;
    int rem = id % 98304;
    int c = rem >> 15, q = rem & 32767;
    int col = q >> 7, k = q & 127;
    int z = hlf ? k : (128 + k);
    float wv = (col < 128) ? wf[((size_t)c * NZ + z) * ND + col]
                           : wsg[((size_t)c * NZ + z) * ND + (col - 128)];
    f16 h, l; split1(wv, h, l);
    if (hlf) { WsT_hi[rem] = h; WsT_lo[rem] = l; }
    else     { WmT_hi[rem] = h; WmT_lo[rem] = l; }
}

// ---- EW[c][type][j] = sum_k edge_w[type][k] * W[c][256+k][j]  (fp32 exact) ----
__global__ __launch_bounds__(256) void ew_kernel(
    const float* __restrict__ edge_w, const float* __restrict__ wf,
    const float* __restrict__ wsg, float* __restrict__ EW)
{
    __shared__ float se[128];
    int c = blockIdx.x / VOCAB, ty = blockIdx.x % VOCAB;
    int j = threadIdx.x;
    if (j < 128) se[j] = edge_w[(size_t)ty * ND + j];
    __syncthreads();
    const float* W = (j < 128) ? wf : wsg;
    int col = j & 127;
    float acc = 0.f;
    #pragma unroll 8
    for (int k = 0; k < 128; ++k)
        acc = fmaf(se[k], W[((size_t)c * NZ + 256 + k) * ND + col], acc);
    EW[((size_t)c * VOCAB + ty) * 256 + j] = acc;
}

// ---- embed: v = node_w[type]*m + slot -> hi/lo split ----
__global__ __launch_bounds__(256) void embed_kernel(
    const int* __restrict__ node_types, const float* __restrict__ slot_types,
    const float* __restrict__ node_w, f16* __restrict__ vhi, f16* __restrict__ vlo)
{
    int i = blockIdx.x * 256 + threadIdx.x;
    int bn = i >> 7, d = i & 127;
    int ty = node_types[bn];
    float m = ty >= 0 ? 1.f : 0.f;
    int idx = ty >= 0 ? ty : 0;
    float v = node_w[(size_t)idx * ND + d] * m + slot_types[i];
    f16 h, l; split1(v, h, l);
    vhi[i] = h; vlo[i] = l;
}

// ---- selfacc[node][256] = v . Wself + bias ; 32 nodes/block, 32x32 MFMA ----
__global__ __launch_bounds__(256, 3) void self_gemm_kernel(
    const f16* __restrict__ vhi, const f16* __restrict__ vlo,
    const f16* __restrict__ WsT_hi, const f16* __restrict__ WsT_lo,
    const float* __restrict__ bfv, const float* __restrict__ bsv,
    float* __restrict__ selfacc)
{
    __shared__ __align__(16) char sA[16384];   // hi 32x128 f16 @0, lo @8192
    const int node0 = blockIdx.x * 32;
    const int t = threadIdx.x;
    #pragma unroll
    for (int it = 0; it < 2; ++it) {
        int slot = it * 256 + t;
        int r = slot >> 4, c = slot & 15;
        int cs = c ^ (r & 15);
        size_t src = (size_t)(node0 + r) * ND + cs * 8;
        *(half8*)(sA + r * 256 + c * 16) = *(const half8*)(vhi + src);
        *(half8*)(sA + 8192 + r * 256 + c * 16) = *(const half8*)(vlo + src);
    }
    __syncthreads();
    const int lane = t & 63, w = t >> 6;
    const int l31 = lane & 31, l32 = lane >> 5;
    const f16 ic = (f16)INV_LO;
    const half8 inv8 = {ic, ic, ic, ic, ic, ic, ic, ic};
    floatx16 acc0[2] = {}, acc1[2] = {};
    const int row = l31;
    int colb[2] = { w * 64 + l31, w * 64 + 32 + l31 };
    #pragma unroll
    for (int ks = 0; ks < 8; ++ks) {
        int q = (((ks * 2 + l32) ^ (row & 15)) << 4);
        half8 ah = *(const half8*)(sA + row * 256 + q);
        half8 al = *(const half8*)(sA + 8192 + row * 256 + q);
        half8 alu = al * inv8;
        #pragma unroll
        for (int nt = 0; nt < 2; ++nt) {
            half8 bhv = *(const half8*)(WsT_hi + (size_t)colb[nt] * 128 + ks * 16 + l32 * 8);
            half8 blv = *(const half8*)(WsT_lo + (size_t)colb[nt] * 128 + ks * 16 + l32 * 8);
            acc0[nt] = mfma32(ah, bhv, acc0[nt]);
            acc1[nt] = mfma32(ah, blv, acc1[nt]);
            acc1[nt] = mfma32(al, bhv, acc1[nt]);
            acc1[nt] = mfma32(alu, blv, acc1[nt]);
        }
    }
    #pragma unroll
    for (int nt = 0; nt < 2; ++nt) {
        int col = colb[nt];
        float bias = (col < 128) ? bfv[col] : bsv[col - 128];
        #pragma unroll
        for (int r = 0; r < 16; ++r) {
            int orow = (r & 3) + 8 * (r >> 2) + 4 * l32;
            selfacc[(size_t)(node0 + orow) * 256 + col] =
                acc0[nt][r] + acc1[nt][r] * INV_LO + bias;
        }
    }
}

// ---- main conv: 2 nodes (32 rows: 12 real + 4 pad each) per block ----
__global__ __launch_bounds__(256, 3) void conv_mfma_kernel(
    const f16* __restrict__ vhi, const f16* __restrict__ vlo,
    f16* __restrict__ vhi_out, f16* __restrict__ vlo_out,
    const int* __restrict__ neighbor_list, const int* __restrict__ edge_types,
    const f16* __restrict__ WmT_hi, const f16* __restrict__ WmT_lo,
    const float* __restrict__ selfacc, const float* __restrict__ EW,
    const float* __restrict__ bn_gamma, const float* __restrict__ bn_beta,
    const float* __restrict__ bn_mean, const float* __restrict__ bn_var)
{
    __shared__ __align__(16) char sA[16384];   // A_hi 32x128 f16 @0, A_lo @8192
    __shared__ int s_eid[32];
    __shared__ float s_mask[32];
    __shared__ int s_flags[2][4];

    const int node0 = blockIdx.x * 2;
    const int bb = node0 >> 9;                 // batch index (NN=512)
    const int t = threadIdx.x;

    if (t < 32) {
        int g = t >> 4, l = t & 15;
        int nl = -1, et = -1;
        if (l < 12) {
            nl = neighbor_list[(node0 + g) * NL + l];
            et = edge_types[(node0 + g) * NL + l];
        }
        s_eid[t] = et;
        s_mask[t] = (nl >= 0) ? 1.f : 0.f;
    }
    // stage A rows (pre-split f16); masked/pad rows get finite dummy data (mask kills them)
    #pragma unroll
    for (int it = 0; it < 2; ++it) {
        int slot = it * 256 + t;
        int r = slot >> 4, c = slot & 15;
        int g = r >> 4, l = r & 15;
        int nl = (l < 12) ? neighbor_list[(node0 + g) * NL + l] : -1;
        size_t srcn = (nl >= 0) ? (size_t)(bb * NN + nl) : (size_t)node0;
        int cs = c ^ (r & 15);
        size_t src = srcn * ND + cs * 8;
        *(half8*)(sA + r * 256 + c * 16) = *(const half8*)(vhi + src);
        *(half8*)(sA + 8192 + r * 256 + c * 16) = *(const half8*)(vlo + src);
    }
    __syncthreads();

    const int lane = t & 63, w = t >> 6;
    const int l31 = lane & 31, l32 = lane >> 5;
    const f16 ic = (f16)INV_LO;
    const half8 inv8 = {ic, ic, ic, ic, ic, ic, ic, ic};
    floatx16 acc0[2] = {}, acc1[2] = {};     // [0]=f-half col d, [1]=s-half col 128+d
    const int row = l31;
    const int d = w * 32 + l31;
    const int colb[2] = { d, 128 + d };
    #pragma unroll
    for (int ks = 0; ks < 8; ++ks) {
        int q = (((ks * 2 + l32) ^ (row & 15)) << 4);
        half8 ah = *(const half8*)(sA + row * 256 + q);
        half8 al = *(const half8*)(sA + 8192 + row * 256 + q);
        half8 alu = al * inv8;
        #pragma unroll
        for (int nt = 0; nt < 2; ++nt) {
            half8 bhv = *(const half8*)(WmT_hi + (size_t)colb[nt] * 128 + ks * 16 + l32 * 8);
            half8 blv = *(const half8*)(WmT_lo + (size_t)colb[nt] * 128 + ks * 16 + l32 * 8);
            acc0[nt] = mfma32(ah, bhv, acc0[nt]);
            acc1[nt] = mfma32(ah, blv, acc1[nt]);
            acc1[nt] = mfma32(al, bhv, acc1[nt]);
            acc1[nt] = mfma32(alu, blv, acc1[nt]);
        }
    }

    // ---- in-register epilogue ----
    float sf0 = selfacc[(size_t)node0 * 256 + d];
    float ss0 = selfacc[(size_t)node0 * 256 + 128 + d];
    float sf1 = selfacc[(size_t)(node0 + 1) * 256 + d];
    float ss1 = selfacc[(size_t)(node0 + 1) * 256 + 128 + d];
    float part0 = 0.f, part1 = 0.f;
    #pragma unroll
    for (int r = 0; r < 16; ++r) {
        int orow = (r & 3) + 8 * (r >> 2) + 4 * l32;   // 0..31 ; node = orow>>4
        int nodei = orow >> 4;
        int et = s_eid[orow];
        float m = s_mask[orow];
        float pf = acc0[0][r] + acc1[0][r] * INV_LO + (nodei ? sf1 : sf0);
        float ps = acc0[1][r] + acc1[1][r] * INV_LO + (nodei ? ss1 : ss0);
        if (et >= 0) {
            pf += EW[(size_t)et * 256 + d];
            ps += EW[(size_t)et * 256 + 128 + d];
        }
        float s = fast_sigmoid(pf) * fast_tanh(ps) * m;
        if (nodei) part1 += s; else part0 += s;
    }
    part0 += __shfl_xor(part0, 32);
    part1 += __shfl_xor(part1, 32);

    size_t i0 = (size_t)node0 * ND + d, i1 = (size_t)(node0 + 1) * ND + d;
    float x0 = (float)vhi[i0] + (float)vlo[i0] * INV_LO + part0;
    float x1 = (float)vhi[i1] + (float)vlo[i1] * INV_LO + part1;
    int ok0 = __all(fabsf(x0) > 1e-5f);
    int ok1 = __all(fabsf(x1) > 1e-5f);
    if (lane == 0) { s_flags[0][w] = ok0; s_flags[1][w] = ok1; }
    __syncthreads();
    int valid0 = s_flags[0][0] & s_flags[0][1] & s_flags[0][2] & s_flags[0][3];
    int valid1 = s_flags[1][0] & s_flags[1][1] & s_flags[1][2] & s_flags[1][3];

    if (l32 == 0) {
        float g_ = bn_gamma[d], be = bn_beta[d], mu = bn_mean[d];
        float rsv = __builtin_amdgcn_rcpf(sqrtf(bn_var[d] + BN_EPS));
        float o0 = valid0 ? (g_ * (x0 - mu) * rsv + be) : 0.f;
        float o1 = valid1 ? (g_ * (x1 - mu) * rsv + be) : 0.f;
        f16 h, l;
        split1(o0, h, l); vhi_out[i0] = h; vlo_out[i0] = l;
        split1(o1, h, l); vhi_out[i1] = h; vlo_out[i1] = l;
    }
}

// ---- pool: masked mean over nodes + dense ----
__global__ __launch_bounds__(128) void pool_kernel(
    const f16* __restrict__ vhi, const f16* __restrict__ vlo,
    const int* __restrict__ node_types,
    const float* __restrict__ dense_w, const float* __restrict__ dense_b,
    float* __restrict__ out)
{
    __shared__ float s_part[2];
    const int b = blockIdx.x;
    const int d = threadIdx.x;
    float sum = 0.f, cnt = 0.f;
    for (int n = 0; n < NN; ++n) {
        int ty = node_types[b * NN + n];
        float m = ty >= 0 ? 1.f : 0.f;
        size_t idx = ((size_t)b * NN + n) * ND + d;
        float v = (float)vhi[idx] + (float)vlo[idx] * INV_LO;
        sum += v * m; cnt += m;
    }
    float pv = (sum / cnt) * dense_w[d];
    #pragma unroll
    for (int off = 32; off > 0; off >>= 1) pv += __shfl_down(pv, off);
    if ((threadIdx.x & 63) == 0) s_part[threadIdx.x >> 6] = pv;
    __syncthreads();
    if (threadIdx.x == 0) out[b] = s_part[0] + s_part[1] + dense_b[0];
}

extern "C" void kernel_launch(void* const* d_in, const int* in_sizes, int n_in,
                              void* d_out, int out_size, void* d_ws, size_t ws_size,
                              hipStream_t stream) {
    const int*   node_types    = (const int*)d_in[0];
    const int*   neighbor_list = (const int*)d_in[1];
    const int*   edge_types    = (const int*)d_in[2];
    const float* slot_types    = (const float*)d_in[3];
    const float* node_w        = (const float*)d_in[4];
    const float* edge_w        = (const float*)d_in[5];
    const float* wf            = (const float*)d_in[6];
    const float* bfv           = (const float*)d_in[7];
    const float* wsg           = (const float*)d_in[8];
    const float* bsv           = (const float*)d_in[9];
    const float* bn_gamma      = (const float*)d_in[10];
    const float* bn_beta       = (const float*)d_in[11];
    const float* bn_mean       = (const float*)d_in[12];
    const float* bn_var        = (const float*)d_in[13];
    const float* dense_w       = (const float*)d_in[14];
    const float* dense_b       = (const float*)d_in[15];
    float* out = (float*)d_out;

    float* wsf = (float*)d_ws;
    float* selfacc = wsf;                        // 32768*256 f32
    float* EW      = wsf + 8388608;              // 3*1000*256 f32
    f16* f16base = (f16*)(wsf + 8388608 + 768000);
    f16* vhiA   = f16base;                       // 4,194,304 f16 each
    f16* vloA   = vhiA + 4194304;
    f16* vhiB   = vloA + 4194304;
    f16* vloB   = vhiB + 4194304;
    f16* WmT_hi = vloB + 4194304;                // 3*32768 f16 each
    f16* WmT_lo = WmT_hi + 98304;
    f16* WsT_hi = WmT_lo + 98304;
    f16* WsT_lo = WsT_hi + 98304;

    prep_kernel<<<768, 256, 0, stream>>>(wf, wsg, WmT_hi, WmT_lo, WsT_hi, WsT_lo);
    ew_kernel<<<NCONV * VOCAB, 256, 0, stream>>>(edge_w, wf, wsg, EW);
    embed_kernel<<<(NB * NN * ND) / 256, 256, 0, stream>>>(node_types, slot_types, node_w, vhiA, vloA);

    const f16 *cin_hi = vhiA, *cin_lo = vloA;
    f16 *cout_hi = vhiB, *cout_lo = vloB;
    for (int c = 0; c < NCONV; ++c) {
        self_gemm_kernel<<<(NB * NN) / 32, 256, 0, stream>>>(
            cin_hi, cin_lo, WsT_hi + c * 32768, WsT_lo + c * 32768,
            bfv + c * ND, bsv + c * ND, selfacc);
        conv_mfma_kernel<<<(NB * NN) / 2, 256, 0, stream>>>(
            cin_hi, cin_lo, cout_hi, cout_lo,
            neighbor_list, edge_types,
            WmT_hi + c * 32768, WmT_lo + c * 32768,
            selfacc, EW + (size_t)c * VOCAB * 256,
            bn_gamma + c * ND, bn_beta + c * ND, bn_mean + c * ND, bn_var + c * ND);
        f16* th = (f16*)cin_hi; f16* tl = (f16*)cin_lo;
        cin_hi = cout_hi; cin_lo = cout_lo;
        cout_hi = th; cout_lo = tl;
    }

    pool_kernel<<<NB, 128, 0, stream>>>(cin_hi, cin_lo, node_types, dense_w, dense_b, out);
}

// Round 4
// 678.041 us; speedup vs baseline: 3.5918x; 1.5003x over previous
//
#include <hip/hip_runtime.h>

#define NB 64
#define NN 512
#define NL 12
#define ND 128
#define NZ 384
#define NCONV 3
#define VOCAB 1000
#define BN_EPS 1e-3f
#define LO_SCALE 2048.0f
#define INV_LO (1.0f/2048.0f)
#define TILES 8    // node-pairs per conv block

typedef _Float16 f16;
using half8 = __attribute__((ext_vector_type(8))) _Float16;
using floatx16 = __attribute__((ext_vector_type(16))) float;

__device__ __forceinline__ floatx16 mfma32(half8 a, half8 b, floatx16 c) {
    return __builtin_amdgcn_mfma_f32_32x32x16_f16(a, b, c, 0, 0, 0);
}
__device__ __forceinline__ float fast_sigmoid(float x) {
    return __builtin_amdgcn_rcpf(1.f + __expf(-x));
}
__device__ __forceinline__ float fast_tanh(float x) {
    return 1.f - 2.f * __builtin_amdgcn_rcpf(__expf(2.f * x) + 1.f);
}
__device__ __forceinline__ void split1(float x, f16& h, f16& l) {
    h = (f16)x; l = (f16)((x - (float)h) * LO_SCALE);
}

// ---- weight prep: k-chunk-major layout for coalesced B loads ----
// dst[c][k>>3][col][k&7] : element (col, k) of the transposed/split weight.
// Wm: k -> z = 128+k (neighbor block). Ws: k -> z = k (self block).
// col<128 -> wf column col, col>=128 -> ws column col-128.
__global__ __launch_bounds__(256) void prep_kernel(
    const float* __restrict__ wf, const float* __restrict__ wsg,
    f16* __restrict__ WmT_hi, f16* __restrict__ WmT_lo,
    f16* __restrict__ WsT_hi, f16* __restrict__ WsT_lo)
{
    int id = blockIdx.x * 256 + threadIdx.x;   // 196608 total
    int hlf = id / 98304;
    int rem = id % 98304;
    int c = rem >> 15, q = rem & 32767;
    int col = q >> 7, k = q & 127;
    int z = hlf ? k : (128 + k);
    float wv = (col < 128) ? wf[((size_t)c * NZ + z) * ND + col]
                           : wsg[((size_t)c * NZ + z) * ND + (col - 128)];
    f16 h, l; split1(wv, h, l);
    size_t dst = (size_t)c * 32768 + (size_t)(k >> 3) * 2048 + col * 8 + (k & 7);
    if (hlf) { WsT_hi[dst] = h; WsT_lo[dst] = l; }
    else     { WmT_hi[dst] = h; WmT_lo[dst] = l; }
}

// ---- EWp[c][type][d] = float2{f-part, s-part} of edge contribution (fp32 exact) ----
__global__ __launch_bounds__(256) void ew_kernel(
    const float* __restrict__ edge_w, const float* __restrict__ wf,
    const float* __restrict__ wsg, float* __restrict__ EWp)
{
    __shared__ float se[128];
    int c = blockIdx.x / VOCAB, ty = blockIdx.x % VOCAB;
    int j = threadIdx.x;
    if (j < 128) se[j] = edge_w[(size_t)ty * ND + j];
    __syncthreads();
    const float* W = (j < 128) ? wf : wsg;
    int col = j & 127, h = j >> 7;
    float acc = 0.f;
    #pragma unroll 8
    for (int k = 0; k < 128; ++k)
        acc = fmaf(se[k], W[((size_t)c * NZ + 256 + k) * ND + col], acc);
    EWp[(((size_t)c * VOCAB + ty) * 128 + col) * 2 + h] = acc;
}

// ---- embed: v = node_w[type]*m + slot -> hi/lo split ----
__global__ __launch_bounds__(256) void embed_kernel(
    const int* __restrict__ node_types, const float* __restrict__ slot_types,
    const float* __restrict__ node_w, f16* __restrict__ vhi, f16* __restrict__ vlo)
{
    int i = blockIdx.x * 256 + threadIdx.x;
    int bn = i >> 7, d = i & 127;
    int ty = node_types[bn];
    float m = ty >= 0 ? 1.f : 0.f;
    int idx = ty >= 0 ? ty : 0;
    float v = node_w[(size_t)idx * ND + d] * m + slot_types[i];
    f16 h, l; split1(v, h, l);
    vhi[i] = h; vlo[i] = l;
}

// ---- selfpk[node][d] = float2{v.Wf_self + bf, v.Ws_self + bs} ; 32 nodes/block ----
__global__ __launch_bounds__(256, 2) void self_gemm_kernel(
    const f16* __restrict__ vhi, const f16* __restrict__ vlo,
    const f16* __restrict__ WsT_hi, const f16* __restrict__ WsT_lo,
    const float* __restrict__ bfv, const float* __restrict__ bsv,
    float* __restrict__ selfpk)
{
    __shared__ __align__(16) char sA[16384];   // hi 32x128 f16 @0, lo @8192
    const int node0 = blockIdx.x * 32;
    const int tid = threadIdx.x;
    const int lane = tid & 63, w = tid >> 6;
    const int l31 = lane & 31, l32 = lane >> 5;
    const int colb[2] = { w * 64 + l31, w * 64 + 32 + l31 };

    half8 Bh[2][8], Bl[2][8];
    #pragma unroll
    for (int nt = 0; nt < 2; ++nt)
    #pragma unroll
    for (int ks = 0; ks < 8; ++ks) {
        size_t boff = (size_t)(ks * 2 + l32) * 2048 + colb[nt] * 8;
        Bh[nt][ks] = *(const half8*)(WsT_hi + boff);
        Bl[nt][ks] = *(const half8*)(WsT_lo + boff);
    }
    #pragma unroll
    for (int it = 0; it < 2; ++it) {
        int slot = it * 256 + tid;
        int r = slot >> 4, c = slot & 15;
        int cs = c ^ (r & 15);
        size_t src = (size_t)(node0 + r) * ND + cs * 8;
        *(half8*)(sA + r * 256 + c * 16) = *(const half8*)(vhi + src);
        *(half8*)(sA + 8192 + r * 256 + c * 16) = *(const half8*)(vlo + src);
    }
    __syncthreads();

    floatx16 acc0[2] = {}, acc1[2] = {};
    #pragma unroll
    for (int ks = 0; ks < 8; ++ks) {
        int q = (((ks * 2 + l32) ^ (l31 & 15)) << 4);
        half8 ah = *(const half8*)(sA + l31 * 256 + q);
        half8 al = *(const half8*)(sA + 8192 + l31 * 256 + q);
        #pragma unroll
        for (int nt = 0; nt < 2; ++nt) {
            acc0[nt] = mfma32(ah, Bh[nt][ks], acc0[nt]);
            acc1[nt] = mfma32(ah, Bl[nt][ks], acc1[nt]);
            acc1[nt] = mfma32(al, Bh[nt][ks], acc1[nt]);
        }
    }
    #pragma unroll
    for (int nt = 0; nt < 2; ++nt) {
        int col = colb[nt];
        float bias = (col < 128) ? bfv[col] : bsv[col - 128];
        int h = col >> 7, dd = col & 127;
        #pragma unroll
        for (int r = 0; r < 16; ++r) {
            int orow = (r & 3) + 8 * (r >> 2) + 4 * l32;
            selfpk[((size_t)(node0 + orow) * 128 + dd) * 2 + h] =
                acc0[nt][r] + acc1[nt][r] * INV_LO + bias;
        }
    }
}

// ---- main conv: 16 nodes / block, 8 tiles of 2 nodes, B in registers ----
// A-tile rows: 0..11 = node0 l, 12..23 = node1 l, 24..31 = pad.
__global__ __launch_bounds__(256, 2) void conv_mfma_kernel(
    const f16* __restrict__ vhi, const f16* __restrict__ vlo,
    f16* __restrict__ vhi_out, f16* __restrict__ vlo_out,
    const int* __restrict__ neighbor_list, const int* __restrict__ edge_types,
    const f16* __restrict__ WmT_hi, const f16* __restrict__ WmT_lo,
    const float* __restrict__ selfpk, const float* __restrict__ EWp,
    const float* __restrict__ bn_gamma, const float* __restrict__ bn_beta,
    const float* __restrict__ bn_mean, const float* __restrict__ bn_var)
{
    __shared__ __align__(16) char sA[2][16384];   // per buf: hi 32x256B @0, lo @8192
    __shared__ int   s_eid[2][24];
    __shared__ float s_mask[2][24];
    __shared__ int   s_flags[2][2][4];

    const int tid = threadIdx.x;
    const int lane = tid & 63, w = tid >> 6;
    const int l31 = lane & 31, l32 = lane >> 5;
    const int d = w * 32 + l31;
    const int nbase = blockIdx.x * (2 * TILES);
    const int bbase = (nbase >> 9) << 9;

    // B into registers first (in flight during prologue staging)
    half8 Bh[2][8], Bl[2][8];
    #pragma unroll
    for (int ks = 0; ks < 8; ++ks) {
        size_t k0 = (size_t)(ks * 2 + l32) * 2048;
        Bh[0][ks] = *(const half8*)(WmT_hi + k0 + d * 8);
        Bl[0][ks] = *(const half8*)(WmT_lo + k0 + d * 8);
        Bh[1][ks] = *(const half8*)(WmT_hi + k0 + (128 + d) * 8);
        Bl[1][ks] = *(const half8*)(WmT_lo + k0 + (128 + d) * 8);
    }

    const float g_ = bn_gamma[d], be = bn_beta[d], mu = bn_mean[d];
    const float rsv = __builtin_amdgcn_rcpf(sqrtf(bn_var[d] + BN_EPS));

    // prologue: stage tile 0 into buf 0
    if (tid < 24) {
        int g = tid >= 12, l = tid - g * 12;
        int node = nbase + g;
        int nl = neighbor_list[node * NL + l];
        s_eid[0][tid] = edge_types[node * NL + l];
        s_mask[0][tid] = (nl >= 0) ? 1.f : 0.f;
    }
    #pragma unroll
    for (int it = 0; it < 2; ++it) {
        int slot = it * 256 + tid;
        int r = slot >> 4, c = slot & 15;
        int srcn = nbase;
        if (r < 24) {
            int g = r >= 12, l = r - g * 12;
            int nl = neighbor_list[(nbase + g) * NL + l];
            srcn = (nl >= 0) ? (bbase + nl) : nbase;
        }
        int cs = c ^ (r & 15);
        size_t off = (size_t)srcn * ND + cs * 8;
        *(half8*)(&sA[0][r * 256 + c * 16]) = *(const half8*)(vhi + off);
        *(half8*)(&sA[0][8192 + r * 256 + c * 16]) = *(const half8*)(vlo + off);
    }
    __syncthreads();

    for (int t = 0; t < TILES; ++t) {
        const int cur = t & 1, nxt = cur ^ 1;
        const int tn0 = nbase + 2 * t;

        // issue next-tile staging loads early (latency hides under k-loop)
        half8 sh0, sl0, sh1, sl1;
        int wo0 = 0, wo1 = 0;
        const bool do_stage = (t + 1 < TILES);
        if (do_stage) {
            const int tn1 = tn0 + 2;
            if (tid < 24) {
                int g = tid >= 12, l = tid - g * 12;
                int node = tn1 + g;
                int nl = neighbor_list[node * NL + l];
                s_eid[nxt][tid] = edge_types[node * NL + l];
                s_mask[nxt][tid] = (nl >= 0) ? 1.f : 0.f;
            }
            #pragma unroll
            for (int it = 0; it < 2; ++it) {
                int slot = it * 256 + tid;
                int r = slot >> 4, c = slot & 15;
                int srcn = tn1;
                if (r < 24) {
                    int g = r >= 12, l = r - g * 12;
                    int nl = neighbor_list[(tn1 + g) * NL + l];
                    srcn = (nl >= 0) ? (bbase + nl) : tn1;
                }
                int cs = c ^ (r & 15);
                size_t off = (size_t)srcn * ND + cs * 8;
                if (it == 0) { wo0 = r * 256 + c * 16; sh0 = *(const half8*)(vhi + off); sl0 = *(const half8*)(vlo + off); }
                else         { wo1 = r * 256 + c * 16; sh1 = *(const half8*)(vhi + off); sl1 = *(const half8*)(vlo + off); }
            }
        }

        // k-loop: pure LDS + MFMA (B in regs)
        floatx16 acc0[2] = {}, acc1[2] = {};
        const char* base = &sA[cur][0];
        #pragma unroll
        for (int ks = 0; ks < 8; ++ks) {
            int q = (((ks * 2 + l32) ^ (l31 & 15)) << 4);
            half8 ah = *(const half8*)(base + l31 * 256 + q);
            half8 al = *(const half8*)(base + 8192 + l31 * 256 + q);
            acc0[0] = mfma32(ah, Bh[0][ks], acc0[0]);
            acc1[0] = mfma32(ah, Bl[0][ks], acc1[0]);
            acc1[0] = mfma32(al, Bh[0][ks], acc1[0]);
            acc0[1] = mfma32(ah, Bh[1][ks], acc0[1]);
            acc1[1] = mfma32(ah, Bl[1][ks], acc1[1]);
            acc1[1] = mfma32(al, Bh[1][ks], acc1[1]);
        }

        // write staged tile t+1 (loads have had the whole k-loop to land)
        if (do_stage) {
            *(half8*)(&sA[nxt][wo0]) = sh0;
            *(half8*)(&sA[nxt][8192 + wo0]) = sl0;
            *(half8*)(&sA[nxt][wo1]) = sh1;
            *(half8*)(&sA[nxt][8192 + wo1]) = sl1;
        }

        // epilogue part 1: activations, l-sum, x, validity flags
        float2 sp0 = *(const float2*)(selfpk + ((size_t)tn0 * 128 + d) * 2);
        float2 sp1 = *(const float2*)(selfpk + ((size_t)(tn0 + 1) * 128 + d) * 2);
        float part0 = 0.f, part1 = 0.f;
        #pragma unroll
        for (int r = 0; r < 12; ++r) {               // rows 24..31 are pad: skipped
            int orow = (r & 3) + 8 * (r >> 2) + 4 * l32;   // 0..23
            int n1 = orow >= 12;
            int et = s_eid[cur][orow];
            float m = s_mask[cur][orow];
            float ewx = 0.f, ewy = 0.f;
            if (et >= 0) {
                float2 e2 = *(const float2*)(EWp + ((size_t)et * 128 + d) * 2);
                ewx = e2.x; ewy = e2.y;
            }
            float pf = acc0[0][r] + acc1[0][r] * INV_LO + (n1 ? sp1.x : sp0.x) + ewx;
            float ps = acc0[1][r] + acc1[1][r] * INV_LO + (n1 ? sp1.y : sp0.y) + ewy;
            float s = fast_sigmoid(pf) * fast_tanh(ps) * m;
            if (n1) part1 += s; else part0 += s;
        }
        part0 += __shfl_xor(part0, 32);
        part1 += __shfl_xor(part1, 32);

        size_t i0 = (size_t)tn0 * ND + d, i1 = i0 + ND;
        float x0 = (float)vhi[i0] + (float)vlo[i0] * INV_LO + part0;
        float x1 = (float)vhi[i1] + (float)vlo[i1] * INV_LO + part1;
        int ok0 = __all(fabsf(x0) > 1e-5f);
        int ok1 = __all(fabsf(x1) > 1e-5f);
        if (lane == 0) { s_flags[cur][0][w] = ok0; s_flags[cur][1][w] = ok1; }
        __syncthreads();

        // epilogue part 2: BN + store (post-barrier; touches only s_flags + globals)
        int valid0 = s_flags[cur][0][0] & s_flags[cur][0][1] & s_flags[cur][0][2] & s_flags[cur][0][3];
        int valid1 = s_flags[cur][1][0] & s_flags[cur][1][1] & s_flags[cur][1][2] & s_flags[cur][1][3];
        if (l32 == 0) {
            float o0 = valid0 ? (g_ * (x0 - mu) * rsv + be) : 0.f;
            float o1 = valid1 ? (g_ * (x1 - mu) * rsv + be) : 0.f;
            f16 h, l;
            split1(o0, h, l); vhi_out[i0] = h; vlo_out[i0] = l;
            split1(o1, h, l); vhi_out[i1] = h; vlo_out[i1] = l;
        }
    }
}

// ---- pool: masked mean over nodes + dense ----
__global__ __launch_bounds__(128) void pool_kernel(
    const f16* __restrict__ vhi, const f16* __restrict__ vlo,
    const int* __restrict__ node_types,
    const float* __restrict__ dense_w, const float* __restrict__ dense_b,
    float* __restrict__ out)
{
    __shared__ float s_part[2];
    const int b = blockIdx.x;
    const int d = threadIdx.x;
    float sum = 0.f, cnt = 0.f;
    for (int n = 0; n < NN; ++n) {
        int ty = node_types[b * NN + n];
        float m = ty >= 0 ? 1.f : 0.f;
        size_t idx = ((size_t)b * NN + n) * ND + d;
        float v = (float)vhi[idx] + (float)vlo[idx] * INV_LO;
        sum += v * m; cnt += m;
    }
    float pv = (sum / cnt) * dense_w[d];
    #pragma unroll
    for (int off = 32; off > 0; off >>= 1) pv += __shfl_down(pv, off);
    if ((threadIdx.x & 63) == 0) s_part[threadIdx.x >> 6] = pv;
    __syncthreads();
    if (threadIdx.x == 0) out[b] = s_part[0] + s_part[1] + dense_b[0];
}

extern "C" void kernel_launch(void* const* d_in, const int* in_sizes, int n_in,
                              void* d_out, int out_size, void* d_ws, size_t ws_size,
                              hipStream_t stream) {
    const int*   node_types    = (const int*)d_in[0];
    const int*   neighbor_list = (const int*)d_in[1];
    const int*   edge_types    = (const int*)d_in[2];
    const float* slot_types    = (const float*)d_in[3];
    const float* node_w        = (const float*)d_in[4];
    const float* edge_w        = (const float*)d_in[5];
    const float* wf            = (const float*)d_in[6];
    const float* bfv           = (const float*)d_in[7];
    const float* wsg           = (const float*)d_in[8];
    const float* bsv           = (const float*)d_in[9];
    const float* bn_gamma      = (const float*)d_in[10];
    const float* bn_beta       = (const float*)d_in[11];
    const float* bn_mean       = (const float*)d_in[12];
    const float* bn_var        = (const float*)d_in[13];
    const float* dense_w       = (const float*)d_in[14];
    const float* dense_b       = (const float*)d_in[15];
    float* out = (float*)d_out;

    float* wsf = (float*)d_ws;
    float* selfpk = wsf;                          // 32768*128*2 f32
    float* EWp    = wsf + 8388608;                // 3*1000*128*2 f32
    f16* f16base = (f16*)(wsf + 8388608 + 768000);
    f16* vhiA   = f16base;                        // 4,194,304 f16 each
    f16* vloA   = vhiA + 4194304;
    f16* vhiB   = vloA + 4194304;
    f16* vloB   = vhiB + 4194304;
    f16* WmT_hi = vloB + 4194304;                 // 3*32768 f16 each
    f16* WmT_lo = WmT_hi + 98304;
    f16* WsT_hi = WmT_lo + 98304;
    f16* WsT_lo = WsT_hi + 98304;

    prep_kernel<<<768, 256, 0, stream>>>(wf, wsg, WmT_hi, WmT_lo, WsT_hi, WsT_lo);
    ew_kernel<<<NCONV * VOCAB, 256, 0, stream>>>(edge_w, wf, wsg, EWp);
    embed_kernel<<<(NB * NN * ND) / 256, 256, 0, stream>>>(node_types, slot_types, node_w, vhiA, vloA);

    const f16 *cin_hi = vhiA, *cin_lo = vloA;
    f16 *cout_hi = vhiB, *cout_lo = vloB;
    for (int c = 0; c < NCONV; ++c) {
        self_gemm_kernel<<<(NB * NN) / 32, 256, 0, stream>>>(
            cin_hi, cin_lo, WsT_hi + c * 32768, WsT_lo + c * 32768,
            bfv + c * ND, bsv + c * ND, selfpk);
        conv_mfma_kernel<<<(NB * NN) / (2 * TILES), 256, 0, stream>>>(
            cin_hi, cin_lo, cout_hi, cout_lo,
            neighbor_list, edge_types,
            WmT_hi + c * 32768, WmT_lo + c * 32768,
            selfpk, EWp + (size_t)c * VOCAB * 256,
            bn_gamma + c * ND, bn_beta + c * ND, bn_mean + c * ND, bn_var + c * ND);
        f16* th = (f16*)cin_hi; f16* tl = (f16*)cin_lo;
        cin_hi = cout_hi; cin_lo = cout_lo;
        cout_hi = th; cout_lo = tl;
    }

    pool_kernel<<<NB, 128, 0, stream>>>(cin_hi, cin_lo, node_types, dense_w, dense_b, out);
}

// Round 5
// 364.961 us; speedup vs baseline: 6.6729x; 1.8578x over previous
//
#include <hip/hip_runtime.h>

#define NB 64
#define NN 512
#define NL 12
#define ND 128
#define NZ 384
#define NCONV 3
#define VOCAB 1000
#define BN_EPS 1e-3f
#define LO_SCALE 2048.0f
#define INV_LO (1.0f/2048.0f)

typedef _Float16 f16;
using half8 = __attribute__((ext_vector_type(8))) _Float16;
using floatx16 = __attribute__((ext_vector_type(16))) float;

__device__ __forceinline__ floatx16 mfma32(half8 a, half8 b, floatx16 c) {
    return __builtin_amdgcn_mfma_f32_32x32x16_f16(a, b, c, 0, 0, 0);
}
__device__ __forceinline__ float fast_sigmoid(float x) {
    return __builtin_amdgcn_rcpf(1.f + __expf(-x));
}
__device__ __forceinline__ float fast_tanh(float x) {
    return 1.f - 2.f * __builtin_amdgcn_rcpf(__expf(2.f * x) + 1.f);
}
__device__ __forceinline__ void split1(float x, f16& h, f16& l) {
    h = (f16)x; l = (f16)((x - (float)h) * LO_SCALE);
}

// ---- prep: concatenated weight, k-chunk-major, f16 hi/lo ----
// col part: 0=P_f (wf, z=128+k), 1=P_s (ws, z=128+k), 2=S_f (wf, z=k), 3=S_s (ws, z=k)
// dst[c][k>>3][col][k&7]
__global__ __launch_bounds__(256) void prep_kernel(
    const float* __restrict__ wf, const float* __restrict__ wsg,
    f16* __restrict__ Wc_hi, f16* __restrict__ Wc_lo)
{
    int id = blockIdx.x * 256 + threadIdx.x;   // 196608
    int c = id >> 16;
    int rem = id & 65535;
    int col = rem >> 7, k = rem & 127;
    int part = col >> 7;
    int d = col & 127;
    int z = (part < 2) ? (128 + k) : k;
    const float* W = (part & 1) ? wsg : wf;
    float wv = W[((size_t)c * NZ + z) * ND + d];
    f16 h, l; split1(wv, h, l);
    size_t dst = (size_t)c * 65536 + (size_t)(k >> 3) * 4096 + col * 8 + (k & 7);
    Wc_hi[dst] = h; Wc_lo[dst] = l;
}

// ---- EWp[c][type][d] = float2{f,s} edge contribution (fp32 exact), 32 types/block ----
__global__ __launch_bounds__(256) void ew_kernel(
    const float* __restrict__ edge_w, const float* __restrict__ wf,
    const float* __restrict__ wsg, float* __restrict__ EWp)
{
    __shared__ float se[32][128];
    const int c = blockIdx.x >> 5;
    const int tyg = (blockIdx.x & 31) * 32;
    const int tid = threadIdx.x;
    for (int i = tid; i < 4096; i += 256) {
        int ty = i >> 7, k = i & 127;
        int tyv = tyg + ty;
        se[ty][k] = (tyv < VOCAB) ? edge_w[(size_t)tyv * ND + k] : 0.f;
    }
    __syncthreads();
    const int h = tid >> 7, col = tid & 127;
    const float* W = h ? wsg : wf;
    float acc[32];
    #pragma unroll
    for (int ty = 0; ty < 32; ++ty) acc[ty] = 0.f;
    #pragma unroll 4
    for (int k = 0; k < 128; ++k) {
        float wv = W[((size_t)c * NZ + 256 + k) * ND + col];
        #pragma unroll
        for (int ty = 0; ty < 32; ++ty) acc[ty] = fmaf(se[ty][k], wv, acc[ty]);
    }
    #pragma unroll
    for (int ty = 0; ty < 32; ++ty) {
        int tyv = tyg + ty;
        if (tyv < VOCAB)
            EWp[(((size_t)c * VOCAB + tyv) * 128 + col) * 2 + h] = acc[ty];
    }
}

// ---- embed: v = node_w[type]*m + slot -> hi/lo split ----
__global__ __launch_bounds__(256) void embed_kernel(
    const int* __restrict__ node_types, const float* __restrict__ slot_types,
    const float* __restrict__ node_w, f16* __restrict__ vhi, f16* __restrict__ vlo)
{
    int i = blockIdx.x * 256 + threadIdx.x;
    int bn = i >> 7, d = i & 127;
    int ty = node_types[bn];
    float m = ty >= 0 ? 1.f : 0.f;
    int idx = ty >= 0 ? ty : 0;
    float v = node_w[(size_t)idx * ND + d] * m + slot_types[i];
    f16 h, l; split1(v, h, l);
    vhi[i] = h; vlo[i] = l;
}

// ---- PS-GEMM: [32768 x 128] @ [128 x 512] -> Ppk (cols 0-255), Spk (cols 256-511 + bias) ----
// grid (1024, 2): blockIdx.y = half. 32 nodes per block. float2-packed outputs.
__global__ __launch_bounds__(256, 3) void psgemm_kernel(
    const f16* __restrict__ vhi, const f16* __restrict__ vlo,
    const f16* __restrict__ Wc_hi, const f16* __restrict__ Wc_lo,  // pre-offset by conv
    const float* __restrict__ bfv, const float* __restrict__ bsv,  // pre-offset by conv
    float* __restrict__ Ppk, float* __restrict__ Spk)
{
    __shared__ __align__(16) char sA[16384];   // hi 32x256B @0, lo @8192 (XOR-swizzled)
    const int node0 = blockIdx.x * 32;
    const int half = blockIdx.y;
    const int tid = threadIdx.x;
    const int lane = tid & 63, w = tid >> 6;
    const int l31 = lane & 31, l32 = lane >> 5;

    #pragma unroll
    for (int it = 0; it < 2; ++it) {
        int slot = it * 256 + tid;
        int r = slot >> 4, cc = slot & 15;
        int cs = cc ^ (r & 15);
        size_t src = (size_t)(node0 + r) * ND + cs * 8;
        *(half8*)(sA + r * 256 + cc * 16) = *(const half8*)(vhi + src);
        *(half8*)(sA + 8192 + r * 256 + cc * 16) = *(const half8*)(vlo + src);
    }
    __syncthreads();

    const int dcol = w * 32 + l31;
    const int col0 = half * 256 + dcol;     // f-part column
    const int col1 = col0 + 128;            // s-part column

    floatx16 a00 = {}, a10 = {}, a01 = {}, a11 = {};

    int ch0 = l32;
    half8 b0h = *(const half8*)(Wc_hi + (size_t)ch0 * 4096 + col0 * 8);
    half8 b0l = *(const half8*)(Wc_lo + (size_t)ch0 * 4096 + col0 * 8);
    half8 b1h = *(const half8*)(Wc_hi + (size_t)ch0 * 4096 + col1 * 8);
    half8 b1l = *(const half8*)(Wc_lo + (size_t)ch0 * 4096 + col1 * 8);

    #pragma unroll
    for (int ks = 0; ks < 8; ++ks) {
        half8 n0h, n0l, n1h, n1l;
        if (ks < 7) {
            int nch = (ks + 1) * 2 + l32;
            n0h = *(const half8*)(Wc_hi + (size_t)nch * 4096 + col0 * 8);
            n0l = *(const half8*)(Wc_lo + (size_t)nch * 4096 + col0 * 8);
            n1h = *(const half8*)(Wc_hi + (size_t)nch * 4096 + col1 * 8);
            n1l = *(const half8*)(Wc_lo + (size_t)nch * 4096 + col1 * 8);
        }
        int q = (((ks * 2 + l32) ^ (l31 & 15)) << 4);
        half8 ah = *(const half8*)(sA + l31 * 256 + q);
        half8 al = *(const half8*)(sA + 8192 + l31 * 256 + q);
        a00 = mfma32(ah, b0h, a00);
        a10 = mfma32(ah, b0l, a10);
        a10 = mfma32(al, b0h, a10);
        a01 = mfma32(ah, b1h, a01);
        a11 = mfma32(ah, b1l, a11);
        a11 = mfma32(al, b1h, a11);
        b0h = n0h; b0l = n0l; b1h = n1h; b1l = n1l;
    }

    float bx = 0.f, by = 0.f;
    if (half) { bx = bfv[dcol]; by = bsv[dcol]; }
    float* outp = half ? Spk : Ppk;
    #pragma unroll
    for (int r = 0; r < 16; ++r) {
        int orow = (r & 3) + 8 * (r >> 2) + 4 * l32;
        float2 v2 = { a00[r] + a10[r] * INV_LO + bx,
                      a01[r] + a11[r] * INV_LO + by };
        *(float2*)(outp + ((size_t)(node0 + orow) * 128 + dcol) * 2) = v2;
    }
}

// ---- edge epilogue: gather P[nb]+S[n]+EW[et], activate, l-sum, BN; v updated IN PLACE ----
__global__ __launch_bounds__(256) void edge_epilogue_kernel(
    f16* __restrict__ vhi, f16* __restrict__ vlo,
    const int* __restrict__ neighbor_list, const int* __restrict__ edge_types,
    const float* __restrict__ Ppk, const float* __restrict__ Spk,
    const float* __restrict__ EWp,
    const float* __restrict__ bn_gamma, const float* __restrict__ bn_beta,
    const float* __restrict__ bn_mean, const float* __restrict__ bn_var)
{
    __shared__ int s_nl[2][12], s_et[2][12];
    __shared__ int s_flags[2][2];
    const int node0 = blockIdx.x * 2;
    const int tid = threadIdx.x;
    if (tid < 24) {
        int g = tid >= 12, l = tid - g * 12;
        s_nl[g][l] = neighbor_list[(node0 + g) * NL + l];
        s_et[g][l] = edge_types[(node0 + g) * NL + l];
    }
    __syncthreads();
    const int g = tid >> 7, d = tid & 127;
    const int node = node0 + g;
    const int bbase = node & ~(NN - 1);
    float2 sp2 = *(const float2*)(Spk + ((size_t)node * 128 + d) * 2);
    float sum = 0.f;
    #pragma unroll
    for (int l = 0; l < NL; ++l) {
        int nl = s_nl[g][l];
        if (nl >= 0) {
            float2 p2 = *(const float2*)(Ppk + ((size_t)(bbase + nl) * 128 + d) * 2);
            int et = s_et[g][l];
            float ex = 0.f, ey = 0.f;
            if (et >= 0) {
                float2 e2 = *(const float2*)(EWp + ((size_t)et * 128 + d) * 2);
                ex = e2.x; ey = e2.y;
            }
            float pf = p2.x + sp2.x + ex;
            float ps = p2.y + sp2.y + ey;
            sum += fast_sigmoid(pf) * fast_tanh(ps);
        }
    }
    size_t ix = (size_t)node * ND + d;
    float x = (float)vhi[ix] + (float)vlo[ix] * INV_LO + sum;
    int ok = __all(fabsf(x) > 1e-5f);
    int w2 = (tid >> 6) & 1;
    if ((tid & 63) == 0) s_flags[g][w2] = ok;
    __syncthreads();
    int valid = s_flags[g][0] & s_flags[g][1];
    float gm = bn_gamma[d], be = bn_beta[d], mu = bn_mean[d];
    float rsv = __builtin_amdgcn_rcpf(sqrtf(bn_var[d] + BN_EPS));
    float o = valid ? (gm * (x - mu) * rsv + be) : 0.f;
    f16 h, l2; split1(o, h, l2);
    vhi[ix] = h; vlo[ix] = l2;
}

// ---- pool: masked mean over nodes + dense ----
__global__ __launch_bounds__(128) void pool_kernel(
    const f16* __restrict__ vhi, const f16* __restrict__ vlo,
    const int* __restrict__ node_types,
    const float* __restrict__ dense_w, const float* __restrict__ dense_b,
    float* __restrict__ out)
{
    __shared__ float s_part[2];
    const int b = blockIdx.x;
    const int d = threadIdx.x;
    float sum = 0.f, cnt = 0.f;
    for (int n = 0; n < NN; ++n) {
        int ty = node_types[b * NN + n];
        float m = ty >= 0 ? 1.f : 0.f;
        size_t idx = ((size_t)b * NN + n) * ND + d;
        float v = (float)vhi[idx] + (float)vlo[idx] * INV_LO;
        sum += v * m; cnt += m;
    }
    float pv = (sum / cnt) * dense_w[d];
    #pragma unroll
    for (int off = 32; off > 0; off >>= 1) pv += __shfl_down(pv, off);
    if ((threadIdx.x & 63) == 0) s_part[threadIdx.x >> 6] = pv;
    __syncthreads();
    if (threadIdx.x == 0) out[b] = s_part[0] + s_part[1] + dense_b[0];
}

extern "C" void kernel_launch(void* const* d_in, const int* in_sizes, int n_in,
                              void* d_out, int out_size, void* d_ws, size_t ws_size,
                              hipStream_t stream) {
    const int*   node_types    = (const int*)d_in[0];
    const int*   neighbor_list = (const int*)d_in[1];
    const int*   edge_types    = (const int*)d_in[2];
    const float* slot_types    = (const float*)d_in[3];
    const float* node_w        = (const float*)d_in[4];
    const float* edge_w        = (const float*)d_in[5];
    const float* wf            = (const float*)d_in[6];
    const float* bfv           = (const float*)d_in[7];
    const float* wsg           = (const float*)d_in[8];
    const float* bsv           = (const float*)d_in[9];
    const float* bn_gamma      = (const float*)d_in[10];
    const float* bn_beta       = (const float*)d_in[11];
    const float* bn_mean       = (const float*)d_in[12];
    const float* bn_var        = (const float*)d_in[13];
    const float* dense_w       = (const float*)d_in[14];
    const float* dense_b       = (const float*)d_in[15];
    float* out = (float*)d_out;

    float* wsf = (float*)d_ws;
    float* Ppk = wsf;                              // 8,388,608 f32
    float* Spk = wsf + 8388608;                    // 8,388,608 f32
    float* EWp = wsf + 2 * 8388608;                // 768,000 f32
    f16* f16b  = (f16*)(wsf + 2 * 8388608 + 768000);
    f16* vhiA  = f16b;                             // 4,194,304 f16
    f16* vloA  = vhiA + 4194304;                   // 4,194,304 f16
    f16* Wc_hi = vloA + 4194304;                   // 196,608 f16
    f16* Wc_lo = Wc_hi + 196608;                   // 196,608 f16

    prep_kernel<<<768, 256, 0, stream>>>(wf, wsg, Wc_hi, Wc_lo);
    ew_kernel<<<NCONV * 32, 256, 0, stream>>>(edge_w, wf, wsg, EWp);
    embed_kernel<<<(NB * NN * ND) / 256, 256, 0, stream>>>(node_types, slot_types, node_w, vhiA, vloA);

    for (int c = 0; c < NCONV; ++c) {
        psgemm_kernel<<<dim3(1024, 2), 256, 0, stream>>>(
            vhiA, vloA, Wc_hi + (size_t)c * 65536, Wc_lo + (size_t)c * 65536,
            bfv + c * ND, bsv + c * ND, Ppk, Spk);
        edge_epilogue_kernel<<<(NB * NN) / 2, 256, 0, stream>>>(
            vhiA, vloA, neighbor_list, edge_types,
            Ppk, Spk, EWp + (size_t)c * VOCAB * 256,
            bn_gamma + c * ND, bn_beta + c * ND, bn_mean + c * ND, bn_var + c * ND);
    }

    pool_kernel<<<NB, 128, 0, stream>>>(vhiA, vloA, node_types, dense_w, dense_b, out);
}

// Round 6
// 297.292 us; speedup vs baseline: 8.1918x; 1.2276x over previous
//
#include <hip/hip_runtime.h>

#define NB 64
#define NN 512
#define NL 12
#define ND 128
#define NZ 384
#define NCONV 3
#define VOCAB 1000
#define BN_EPS 1e-3f
#define LO_SCALE 2048.0f
#define INV_LO (1.0f/2048.0f)
#define SCF (-1.4426950408889634f)   // -log2(e): f-part scale
#define SCS ( 2.8853900817779268f)   //  2*log2(e): s-part scale

typedef _Float16 f16;
using half8 = __attribute__((ext_vector_type(8))) _Float16;
using floatx16 = __attribute__((ext_vector_type(16))) float;

__device__ __forceinline__ floatx16 mfma32(half8 a, half8 b, floatx16 c) {
    return __builtin_amdgcn_mfma_f32_32x32x16_f16(a, b, c, 0, 0, 0);
}
__device__ __forceinline__ void split1(float x, f16& h, f16& l) {
    h = (f16)x; l = (f16)((x - (float)h) * LO_SCALE);
}

// ---- prep: concatenated weight, k-chunk-major, f16 hi/lo ----
// col part: 0=P_f (wf, z=128+k), 1=P_s (ws, z=128+k), 2=S_f (wf, z=k), 3=S_s (ws, z=k)
// dst[c][k>>3][col][k&7]
__global__ __launch_bounds__(256) void prep_kernel(
    const float* __restrict__ wf, const float* __restrict__ wsg,
    f16* __restrict__ Wc_hi, f16* __restrict__ Wc_lo)
{
    int id = blockIdx.x * 256 + threadIdx.x;   // 196608
    int c = id >> 16;
    int rem = id & 65535;
    int col = rem >> 7, k = rem & 127;
    int part = col >> 7;
    int d = col & 127;
    int z = (part < 2) ? (128 + k) : k;
    const float* W = (part & 1) ? wsg : wf;
    float wv = W[((size_t)c * NZ + z) * ND + d];
    f16 h, l; split1(wv, h, l);
    size_t dst = (size_t)c * 65536 + (size_t)(k >> 3) * 4096 + col * 8 + (k & 7);
    Wc_hi[dst] = h; Wc_lo[dst] = l;
}

// ---- EWp[c][type][d] = float2{f*SCF, s*SCS}; row VOCAB is all-zero (pad row) ----
__global__ __launch_bounds__(256) void ew_kernel(
    const float* __restrict__ edge_w, const float* __restrict__ wf,
    const float* __restrict__ wsg, float* __restrict__ EWp)
{
    __shared__ float se[32][128];
    const int c = blockIdx.x >> 5;
    const int tyg = (blockIdx.x & 31) * 32;
    const int tid = threadIdx.x;
    for (int i = tid; i < 4096; i += 256) {
        int ty = i >> 7, k = i & 127;
        int tyv = tyg + ty;
        se[ty][k] = (tyv < VOCAB) ? edge_w[(size_t)tyv * ND + k] : 0.f;
    }
    __syncthreads();
    const int h = tid >> 7, col = tid & 127;
    const float* W = h ? wsg : wf;
    const float sc = h ? SCS : SCF;
    float acc[32];
    #pragma unroll
    for (int ty = 0; ty < 32; ++ty) acc[ty] = 0.f;
    #pragma unroll 4
    for (int k = 0; k < 128; ++k) {
        float wv = W[((size_t)c * NZ + 256 + k) * ND + col];
        #pragma unroll
        for (int ty = 0; ty < 32; ++ty) acc[ty] = fmaf(se[ty][k], wv, acc[ty]);
    }
    #pragma unroll
    for (int ty = 0; ty < 32; ++ty) {
        int tyv = tyg + ty;
        if (tyv <= VOCAB)   // include zero pad row at index VOCAB
            EWp[(((size_t)c * (VOCAB + 1) + tyv) * 128 + col) * 2 + h] = acc[ty] * sc;
    }
}

// ---- embed: v = node_w[type]*m + slot -> hi/lo split ----
__global__ __launch_bounds__(256) void embed_kernel(
    const int* __restrict__ node_types, const float* __restrict__ slot_types,
    const float* __restrict__ node_w, f16* __restrict__ vhi, f16* __restrict__ vlo)
{
    int i = blockIdx.x * 256 + threadIdx.x;
    int bn = i >> 7, d = i & 127;
    int ty = node_types[bn];
    float m = ty >= 0 ? 1.f : 0.f;
    int idx = ty >= 0 ? ty : 0;
    float v = node_w[(size_t)idx * ND + d] * m + slot_types[i];
    f16 h, l; split1(v, h, l);
    vhi[i] = h; vlo[i] = l;
}

// ---- PS-GEMM: [32768 x 128] @ [128 x 512] -> Ppk (P part), Spk (S part + bias), scaled ----
__global__ __launch_bounds__(256, 3) void psgemm_kernel(
    const f16* __restrict__ vhi, const f16* __restrict__ vlo,
    const f16* __restrict__ Wc_hi, const f16* __restrict__ Wc_lo,  // pre-offset by conv
    const float* __restrict__ bfv, const float* __restrict__ bsv,  // pre-offset by conv
    float* __restrict__ Ppk, float* __restrict__ Spk)
{
    __shared__ __align__(16) char sA[16384];   // hi 32x256B @0, lo @8192 (XOR-swizzled)
    const int node0 = blockIdx.x * 32;
    const int half = blockIdx.y;
    const int tid = threadIdx.x;
    const int lane = tid & 63, w = tid >> 6;
    const int l31 = lane & 31, l32 = lane >> 5;

    #pragma unroll
    for (int it = 0; it < 2; ++it) {
        int slot = it * 256 + tid;
        int r = slot >> 4, cc = slot & 15;
        int cs = cc ^ (r & 15);
        size_t src = (size_t)(node0 + r) * ND + cs * 8;
        *(half8*)(sA + r * 256 + cc * 16) = *(const half8*)(vhi + src);
        *(half8*)(sA + 8192 + r * 256 + cc * 16) = *(const half8*)(vlo + src);
    }
    __syncthreads();

    const int dcol = w * 32 + l31;
    const int col0 = half * 256 + dcol;     // f-part column
    const int col1 = col0 + 128;            // s-part column

    floatx16 a00 = {}, a10 = {}, a01 = {}, a11 = {};

    int ch0 = l32;
    half8 b0h = *(const half8*)(Wc_hi + (size_t)ch0 * 4096 + col0 * 8);
    half8 b0l = *(const half8*)(Wc_lo + (size_t)ch0 * 4096 + col0 * 8);
    half8 b1h = *(const half8*)(Wc_hi + (size_t)ch0 * 4096 + col1 * 8);
    half8 b1l = *(const half8*)(Wc_lo + (size_t)ch0 * 4096 + col1 * 8);

    #pragma unroll
    for (int ks = 0; ks < 8; ++ks) {
        half8 n0h, n0l, n1h, n1l;
        if (ks < 7) {
            int nch = (ks + 1) * 2 + l32;
            n0h = *(const half8*)(Wc_hi + (size_t)nch * 4096 + col0 * 8);
            n0l = *(const half8*)(Wc_lo + (size_t)nch * 4096 + col0 * 8);
            n1h = *(const half8*)(Wc_hi + (size_t)nch * 4096 + col1 * 8);
            n1l = *(const half8*)(Wc_lo + (size_t)nch * 4096 + col1 * 8);
        }
        int q = (((ks * 2 + l32) ^ (l31 & 15)) << 4);
        half8 ah = *(const half8*)(sA + l31 * 256 + q);
        half8 al = *(const half8*)(sA + 8192 + l31 * 256 + q);
        a00 = mfma32(ah, b0h, a00);
        a10 = mfma32(ah, b0l, a10);
        a10 = mfma32(al, b0h, a10);
        a01 = mfma32(ah, b1h, a01);
        a11 = mfma32(ah, b1l, a11);
        a11 = mfma32(al, b1h, a11);
        b0h = n0h; b0l = n0l; b1h = n1h; b1l = n1l;
    }

    float bx = 0.f, by = 0.f;
    if (half) { bx = bfv[dcol]; by = bsv[dcol]; }
    float* outp = half ? Spk : Ppk;
    #pragma unroll
    for (int r = 0; r < 16; ++r) {
        int orow = (r & 3) + 8 * (r >> 2) + 4 * l32;
        float2 v2 = { (a00[r] + a10[r] * INV_LO + bx) * SCF,
                      (a01[r] + a11[r] * INV_LO + by) * SCS };
        *(float2*)(outp + ((size_t)(node0 + orow) * 128 + dcol) * 2) = v2;
    }
}

// ---- edge epilogue: gather-all-then-compute; v updated IN PLACE ----
__global__ __launch_bounds__(256, 4) void edge_epilogue_kernel(
    f16* __restrict__ vhi, f16* __restrict__ vlo,
    const int* __restrict__ neighbor_list, const int* __restrict__ edge_types,
    const float* __restrict__ Ppk, const float* __restrict__ Spk,
    const float* __restrict__ EWp,
    const float* __restrict__ bn_gamma, const float* __restrict__ bn_beta,
    const float* __restrict__ bn_mean, const float* __restrict__ bn_var)
{
    __shared__ int s_nl[2][12], s_et[2][12];
    __shared__ int s_flags[2][2];
    const int node0 = blockIdx.x * 2;
    const int tid = threadIdx.x;
    if (tid < 24) {
        int g = tid >= 12, l = tid - g * 12;
        s_nl[g][l] = neighbor_list[(node0 + g) * NL + l];
        s_et[g][l] = edge_types[(node0 + g) * NL + l];
    }
    __syncthreads();
    const int g = tid >> 7, d = tid & 127;
    const int node = node0 + g;
    const int bbase = node & ~(NN - 1);

    // issue ALL gathers up front (branchless safe indices), then compute
    float2 sp2 = *(const float2*)(Spk + ((size_t)node * 128 + d) * 2);
    float2 p2[NL], e2[NL];
    float m[NL];
    #pragma unroll
    for (int l = 0; l < NL; ++l) {
        int nl = s_nl[g][l];
        int et = s_et[g][l];
        int ns = (nl >= 0) ? (bbase + nl) : node;     // safe node row
        int es = (et >= 0) ? et : VOCAB;              // zero pad row
        m[l] = (nl >= 0) ? 1.f : 0.f;
        p2[l] = *(const float2*)(Ppk + ((size_t)ns * 128 + d) * 2);
        e2[l] = *(const float2*)(EWp + ((size_t)es * 128 + d) * 2);
    }
    float sum = 0.f;
    #pragma unroll
    for (int l = 0; l < NL; ++l) {
        float pf = p2[l].x + sp2.x + e2[l].x;          // already * -log2e
        float ps = p2[l].y + sp2.y + e2[l].y;          // already * 2*log2e
        float sig = __builtin_amdgcn_rcpf(1.f + __builtin_amdgcn_exp2f(pf));
        float th  = fmaf(-2.f, __builtin_amdgcn_rcpf(__builtin_amdgcn_exp2f(ps) + 1.f), 1.f);
        sum = fmaf(sig * th, m[l], sum);
    }

    size_t ix = (size_t)node * ND + d;
    float x = (float)vhi[ix] + (float)vlo[ix] * INV_LO + sum;
    int ok = __all(fabsf(x) > 1e-5f);
    int w2 = (tid >> 6) & 1;
    if ((tid & 63) == 0) s_flags[g][w2] = ok;
    __syncthreads();
    int valid = s_flags[g][0] & s_flags[g][1];
    float gm = bn_gamma[d], be = bn_beta[d], mu = bn_mean[d];
    float rsv = __builtin_amdgcn_rcpf(sqrtf(bn_var[d] + BN_EPS));
    float o = valid ? (gm * (x - mu) * rsv + be) : 0.f;
    f16 h, l2; split1(o, h, l2);
    vhi[ix] = h; vlo[ix] = l2;
}

// ---- pool stage 1: partial masked sums over 64-node chunks ----
__global__ __launch_bounds__(256) void pool1_kernel(
    const f16* __restrict__ vhi, const f16* __restrict__ vlo,
    const int* __restrict__ node_types, float* __restrict__ partial)
{
    __shared__ float sbuf[128];
    const int b = blockIdx.x >> 3, chunk = blockIdx.x & 7;
    const int d = threadIdx.x & 127, sub = threadIdx.x >> 7;
    const int n0 = chunk * 64 + sub * 32;
    float sum = 0.f;
    #pragma unroll 4
    for (int i = 0; i < 32; ++i) {
        int n = n0 + i;
        int ty = node_types[b * NN + n];
        float mk = ty >= 0 ? 1.f : 0.f;
        size_t ix = ((size_t)(b * NN + n)) * ND + d;
        sum += ((float)vhi[ix] + (float)vlo[ix] * INV_LO) * mk;
    }
    if (sub == 0) sbuf[d] = sum;
    __syncthreads();
    if (sub == 1) partial[(size_t)blockIdx.x * 128 + d] = sbuf[d] + sum;
}

// ---- pool stage 2: combine chunks, mean, dense ----
__global__ __launch_bounds__(128) void pool2_kernel(
    const float* __restrict__ partial, const int* __restrict__ node_types,
    const float* __restrict__ dense_w, const float* __restrict__ dense_b,
    float* __restrict__ out)
{
    __shared__ float s_part[2], s_cnt[2];
    const int b = blockIdx.x;
    const int d = threadIdx.x;
    float sum = 0.f;
    #pragma unroll
    for (int c = 0; c < 8; ++c) sum += partial[(size_t)(b * 8 + c) * 128 + d];
    float cnt = 0.f;
    #pragma unroll
    for (int i = 0; i < 4; ++i)
        cnt += (node_types[b * NN + d + i * 128] >= 0) ? 1.f : 0.f;
    #pragma unroll
    for (int off = 32; off > 0; off >>= 1) cnt += __shfl_xor(cnt, off);
    if ((d & 63) == 0) s_cnt[d >> 6] = cnt;
    __syncthreads();
    float tcnt = s_cnt[0] + s_cnt[1];
    float pv = (sum / tcnt) * dense_w[d];
    #pragma unroll
    for (int off = 32; off > 0; off >>= 1) pv += __shfl_down(pv, off);
    if ((d & 63) == 0) s_part[d >> 6] = pv;
    __syncthreads();
    if (d == 0) out[b] = s_part[0] + s_part[1] + dense_b[0];
}

extern "C" void kernel_launch(void* const* d_in, const int* in_sizes, int n_in,
                              void* d_out, int out_size, void* d_ws, size_t ws_size,
                              hipStream_t stream) {
    const int*   node_types    = (const int*)d_in[0];
    const int*   neighbor_list = (const int*)d_in[1];
    const int*   edge_types    = (const int*)d_in[2];
    const float* slot_types    = (const float*)d_in[3];
    const float* node_w        = (const float*)d_in[4];
    const float* edge_w        = (const float*)d_in[5];
    const float* wf            = (const float*)d_in[6];
    const float* bfv           = (const float*)d_in[7];
    const float* wsg           = (const float*)d_in[8];
    const float* bsv           = (const float*)d_in[9];
    const float* bn_gamma      = (const float*)d_in[10];
    const float* bn_beta       = (const float*)d_in[11];
    const float* bn_mean       = (const float*)d_in[12];
    const float* bn_var        = (const float*)d_in[13];
    const float* dense_w       = (const float*)d_in[14];
    const float* dense_b       = (const float*)d_in[15];
    float* out = (float*)d_out;

    float* wsf = (float*)d_ws;
    float* Ppk = wsf;                              // 8,388,608 f32
    float* Spk = wsf + 8388608;                    // 8,388,608 f32
    float* EWp = wsf + 2 * 8388608;                // 3*1001*256 = 768,768 f32
    float* pp  = EWp + 768768;                     // 65,536 f32 pool partials
    f16* f16b  = (f16*)(pp + 65536);
    f16* vhiA  = f16b;                             // 4,194,304 f16
    f16* vloA  = vhiA + 4194304;                   // 4,194,304 f16
    f16* Wc_hi = vloA + 4194304;                   // 196,608 f16
    f16* Wc_lo = Wc_hi + 196608;                   // 196,608 f16

    prep_kernel<<<768, 256, 0, stream>>>(wf, wsg, Wc_hi, Wc_lo);
    ew_kernel<<<NCONV * 32, 256, 0, stream>>>(edge_w, wf, wsg, EWp);
    embed_kernel<<<(NB * NN * ND) / 256, 256, 0, stream>>>(node_types, slot_types, node_w, vhiA, vloA);

    for (int c = 0; c < NCONV; ++c) {
        psgemm_kernel<<<dim3(1024, 2), 256, 0, stream>>>(
            vhiA, vloA, Wc_hi + (size_t)c * 65536, Wc_lo + (size_t)c * 65536,
            bfv + c * ND, bsv + c * ND, Ppk, Spk);
        edge_epilogue_kernel<<<(NB * NN) / 2, 256, 0, stream>>>(
            vhiA, vloA, neighbor_list, edge_types,
            Ppk, Spk, EWp + (size_t)c * (VOCAB + 1) * 256,
            bn_gamma + c * ND, bn_beta + c * ND, bn_mean + c * ND, bn_var + c * ND);
    }

    pool1_kernel<<<NB * 8, 256, 0, stream>>>(vhiA, vloA, node_types, pp);
    pool2_kernel<<<NB, 128, 0, stream>>>(pp, node_types, dense_w, dense_b, out);
}

// Round 7
// 289.188 us; speedup vs baseline: 8.4214x; 1.0280x over previous
//
#include <hip/hip_runtime.h>

#define NB 64
#define NN 512
#define NL 12
#define ND 128
#define NZ 384
#define NCONV 3
#define VOCAB 1000
#define BN_EPS 1e-3f
#define LO_SCALE 2048.0f
#define INV_LO (1.0f/2048.0f)
#define SCF (-1.4426950408889634f)   // -log2(e): f-part scale
#define SCS ( 2.8853900817779268f)   //  2*log2(e): s-part scale

typedef _Float16 f16;
using half8 = __attribute__((ext_vector_type(8))) _Float16;
using floatx16 = __attribute__((ext_vector_type(16))) float;

__device__ __forceinline__ floatx16 mfma32(half8 a, half8 b, floatx16 c) {
    return __builtin_amdgcn_mfma_f32_32x32x16_f16(a, b, c, 0, 0, 0);
}
__device__ __forceinline__ void split1(float x, f16& h, f16& l) {
    h = (f16)x; l = (f16)((x - (float)h) * LO_SCALE);
}

// ---- prep: concatenated weight, k-chunk-major, f16 hi/lo ----
// col part: 0=P_f (wf, z=128+k), 1=P_s (ws, z=128+k), 2=S_f (wf, z=k), 3=S_s (ws, z=k)
// dst[c][k>>3][col][k&7]
__global__ __launch_bounds__(256) void prep_kernel(
    const float* __restrict__ wf, const float* __restrict__ wsg,
    f16* __restrict__ Wc_hi, f16* __restrict__ Wc_lo)
{
    int id = blockIdx.x * 256 + threadIdx.x;   // 196608
    int c = id >> 16;
    int rem = id & 65535;
    int col = rem >> 7, k = rem & 127;
    int part = col >> 7;
    int d = col & 127;
    int z = (part < 2) ? (128 + k) : k;
    const float* W = (part & 1) ? wsg : wf;
    float wv = W[((size_t)c * NZ + z) * ND + d];
    f16 h, l; split1(wv, h, l);
    size_t dst = (size_t)c * 65536 + (size_t)(k >> 3) * 4096 + col * 8 + (k & 7);
    Wc_hi[dst] = h; Wc_lo[dst] = l;
}

// ---- EWp[c][type][d] = float2{f*SCF, s*SCS}; row VOCAB is all-zero (pad row) ----
__global__ __launch_bounds__(256) void ew_kernel(
    const float* __restrict__ edge_w, const float* __restrict__ wf,
    const float* __restrict__ wsg, float* __restrict__ EWp)
{
    __shared__ float se[32][128];
    const int c = blockIdx.x >> 5;
    const int tyg = (blockIdx.x & 31) * 32;
    const int tid = threadIdx.x;
    for (int i = tid; i < 4096; i += 256) {
        int ty = i >> 7, k = i & 127;
        int tyv = tyg + ty;
        se[ty][k] = (tyv < VOCAB) ? edge_w[(size_t)tyv * ND + k] : 0.f;
    }
    __syncthreads();
    const int h = tid >> 7, col = tid & 127;
    const float* W = h ? wsg : wf;
    const float sc = h ? SCS : SCF;
    float acc[32];
    #pragma unroll
    for (int ty = 0; ty < 32; ++ty) acc[ty] = 0.f;
    #pragma unroll 4
    for (int k = 0; k < 128; ++k) {
        float wv = W[((size_t)c * NZ + 256 + k) * ND + col];
        #pragma unroll
        for (int ty = 0; ty < 32; ++ty) acc[ty] = fmaf(se[ty][k], wv, acc[ty]);
    }
    #pragma unroll
    for (int ty = 0; ty < 32; ++ty) {
        int tyv = tyg + ty;
        if (tyv <= VOCAB)   // include zero pad row at index VOCAB
            EWp[(((size_t)c * (VOCAB + 1) + tyv) * 128 + col) * 2 + h] = acc[ty] * sc;
    }
}

// ---- embed: v = node_w[type]*m + slot -> hi/lo split ----
__global__ __launch_bounds__(256) void embed_kernel(
    const int* __restrict__ node_types, const float* __restrict__ slot_types,
    const float* __restrict__ node_w, f16* __restrict__ vhi, f16* __restrict__ vlo)
{
    int i = blockIdx.x * 256 + threadIdx.x;
    int bn = i >> 7, d = i & 127;
    int ty = node_types[bn];
    float m = ty >= 0 ? 1.f : 0.f;
    int idx = ty >= 0 ? ty : 0;
    float v = node_w[(size_t)idx * ND + d] * m + slot_types[i];
    f16 h, l; split1(v, h, l);
    vhi[i] = h; vlo[i] = l;
}

// ---- PS-GEMM: [32768 x 128] @ [128 x 512] -> Ppk (P part), Spk (S part + bias), scaled ----
// 1-D grid 2048, XCD-swizzled so batch b runs on XCD b%8 (keeps Ppk/Spk dirty-local
// in that XCD's L2 for the epilogue that follows).
__global__ __launch_bounds__(256, 3) void psgemm_kernel(
    const f16* __restrict__ vhi, const f16* __restrict__ vlo,
    const f16* __restrict__ Wc_hi, const f16* __restrict__ Wc_lo,  // pre-offset by conv
    const float* __restrict__ bfv, const float* __restrict__ bsv,  // pre-offset by conv
    float* __restrict__ Ppk, float* __restrict__ Spk)
{
    __shared__ __align__(16) char sA[16384];   // hi 32x256B @0, lo @8192 (XOR-swizzled)
    // decode: hw -> (batch with batch%8==hw%8, half, 32-node group)
    const int hw = blockIdx.x;
    const int xcd = hw & 7;
    const int q = hw >> 3;            // [0,256): 8 local batches x 2 halves x 16 groups
    const int bl = q >> 5;            // local batch [0,8)
    const int r = q & 31;
    const int half = r >> 4;
    const int xloc = r & 15;
    const int batch = bl * 8 + xcd;
    const int node0 = batch * NN + xloc * 32;

    const int tid = threadIdx.x;
    const int lane = tid & 63, w = tid >> 6;
    const int l31 = lane & 31, l32 = lane >> 5;

    #pragma unroll
    for (int it = 0; it < 2; ++it) {
        int slot = it * 256 + tid;
        int rr = slot >> 4, cc = slot & 15;
        int cs = cc ^ (rr & 15);
        size_t src = (size_t)(node0 + rr) * ND + cs * 8;
        *(half8*)(sA + rr * 256 + cc * 16) = *(const half8*)(vhi + src);
        *(half8*)(sA + 8192 + rr * 256 + cc * 16) = *(const half8*)(vlo + src);
    }
    __syncthreads();

    const int dcol = w * 32 + l31;
    const int col0 = half * 256 + dcol;     // f-part column
    const int col1 = col0 + 128;            // s-part column

    floatx16 a00 = {}, a10 = {}, a01 = {}, a11 = {};

    int ch0 = l32;
    half8 b0h = *(const half8*)(Wc_hi + (size_t)ch0 * 4096 + col0 * 8);
    half8 b0l = *(const half8*)(Wc_lo + (size_t)ch0 * 4096 + col0 * 8);
    half8 b1h = *(const half8*)(Wc_hi + (size_t)ch0 * 4096 + col1 * 8);
    half8 b1l = *(const half8*)(Wc_lo + (size_t)ch0 * 4096 + col1 * 8);

    #pragma unroll
    for (int ks = 0; ks < 8; ++ks) {
        half8 n0h, n0l, n1h, n1l;
        if (ks < 7) {
            int nch = (ks + 1) * 2 + l32;
            n0h = *(const half8*)(Wc_hi + (size_t)nch * 4096 + col0 * 8);
            n0l = *(const half8*)(Wc_lo + (size_t)nch * 4096 + col0 * 8);
            n1h = *(const half8*)(Wc_hi + (size_t)nch * 4096 + col1 * 8);
            n1l = *(const half8*)(Wc_lo + (size_t)nch * 4096 + col1 * 8);
        }
        int qq = (((ks * 2 + l32) ^ (l31 & 15)) << 4);
        half8 ah = *(const half8*)(sA + l31 * 256 + qq);
        half8 al = *(const half8*)(sA + 8192 + l31 * 256 + qq);
        a00 = mfma32(ah, b0h, a00);
        a10 = mfma32(ah, b0l, a10);
        a10 = mfma32(al, b0h, a10);
        a01 = mfma32(ah, b1h, a01);
        a11 = mfma32(ah, b1l, a11);
        a11 = mfma32(al, b1h, a11);
        b0h = n0h; b0l = n0l; b1h = n1h; b1l = n1l;
    }

    float bx = 0.f, by = 0.f;
    if (half) { bx = bfv[dcol]; by = bsv[dcol]; }
    float* outp = half ? Spk : Ppk;
    #pragma unroll
    for (int rr = 0; rr < 16; ++rr) {
        int orow = (rr & 3) + 8 * (rr >> 2) + 4 * l32;
        float2 v2 = { (a00[rr] + a10[rr] * INV_LO + bx) * SCF,
                      (a01[rr] + a11[rr] * INV_LO + by) * SCS };
        *(float2*)(outp + ((size_t)(node0 + orow) * 128 + dcol) * 2) = v2;
    }
}

// ---- edge epilogue: gather-all-then-compute; v updated IN PLACE ----
// XCD-swizzled: batch b's 256 blocks all on XCD b%8 -> batch working set
// (Ppk/Spk/v windows + EW table ~2.3 MB) resident in one 4 MB L2.
__global__ __launch_bounds__(256, 4) void edge_epilogue_kernel(
    f16* __restrict__ vhi, f16* __restrict__ vlo,
    const int* __restrict__ neighbor_list, const int* __restrict__ edge_types,
    const float* __restrict__ Ppk, const float* __restrict__ Spk,
    const float* __restrict__ EWp,
    const float* __restrict__ bn_gamma, const float* __restrict__ bn_beta,
    const float* __restrict__ bn_mean, const float* __restrict__ bn_var)
{
    __shared__ int s_nl[2][12], s_et[2][12];
    __shared__ int s_flags[2][2];
    // decode: hw -> (batch with batch%8==hw%8, node pair j)
    const int hw = blockIdx.x;
    const int xcd = hw & 7;
    const int q = hw >> 3;            // [0,2048): 8 local batches x 256 pairs
    const int b = (q >> 8) * 8 + xcd;
    const int j = q & 255;
    const int node0 = b * NN + j * 2;

    const int tid = threadIdx.x;
    if (tid < 24) {
        int g = tid >= 12, l = tid - g * 12;
        s_nl[g][l] = neighbor_list[(node0 + g) * NL + l];
        s_et[g][l] = edge_types[(node0 + g) * NL + l];
    }
    __syncthreads();
    const int g = tid >> 7, d = tid & 127;
    const int node = node0 + g;
    const int bbase = b * NN;

    // issue ALL gathers up front (branchless safe indices, wave-uniform scalar bases)
    float2 sp2 = *(const float2*)(Spk + ((size_t)node * 128 + d) * 2);
    float2 p2[NL], e2[NL];
    float m[NL];
    #pragma unroll
    for (int l = 0; l < NL; ++l) {
        int nl = s_nl[g][l];
        int et = s_et[g][l];
        int ns = (nl >= 0) ? (bbase + nl) : node;     // safe node row
        int es = (et >= 0) ? et : VOCAB;              // zero pad row
        ns = __builtin_amdgcn_readfirstlane(ns);
        es = __builtin_amdgcn_readfirstlane(es);
        m[l] = (nl >= 0) ? 1.f : 0.f;
        p2[l] = *(const float2*)(Ppk + ((size_t)ns * 128 + d) * 2);
        e2[l] = *(const float2*)(EWp + ((size_t)es * 128 + d) * 2);
    }
    float sum = 0.f;
    #pragma unroll
    for (int l = 0; l < NL; ++l) {
        float pf = p2[l].x + sp2.x + e2[l].x;          // already * -log2e
        float ps = p2[l].y + sp2.y + e2[l].y;          // already * 2*log2e
        float sig = __builtin_amdgcn_rcpf(1.f + __builtin_amdgcn_exp2f(pf));
        float th  = fmaf(-2.f, __builtin_amdgcn_rcpf(__builtin_amdgcn_exp2f(ps) + 1.f), 1.f);
        sum = fmaf(sig * th, m[l], sum);
    }

    size_t ix = (size_t)node * ND + d;
    float x = (float)vhi[ix] + (float)vlo[ix] * INV_LO + sum;
    int ok = __all(fabsf(x) > 1e-5f);
    int w2 = (tid >> 6) & 1;
    if ((tid & 63) == 0) s_flags[g][w2] = ok;
    __syncthreads();
    int valid = s_flags[g][0] & s_flags[g][1];
    float gm = bn_gamma[d], be = bn_beta[d], mu = bn_mean[d];
    float rsv = __builtin_amdgcn_rcpf(sqrtf(bn_var[d] + BN_EPS));
    float o = valid ? (gm * (x - mu) * rsv + be) : 0.f;
    f16 h, l2; split1(o, h, l2);
    vhi[ix] = h; vlo[ix] = l2;
}

// ---- pool stage 1: partial masked sums over 64-node chunks ----
__global__ __launch_bounds__(256) void pool1_kernel(
    const f16* __restrict__ vhi, const f16* __restrict__ vlo,
    const int* __restrict__ node_types, float* __restrict__ partial)
{
    __shared__ float sbuf[128];
    const int b = blockIdx.x >> 3, chunk = blockIdx.x & 7;
    const int d = threadIdx.x & 127, sub = threadIdx.x >> 7;
    const int n0 = chunk * 64 + sub * 32;
    float sum = 0.f;
    #pragma unroll 4
    for (int i = 0; i < 32; ++i) {
        int n = n0 + i;
        int ty = node_types[b * NN + n];
        float mk = ty >= 0 ? 1.f : 0.f;
        size_t ix = ((size_t)(b * NN + n)) * ND + d;
        sum += ((float)vhi[ix] + (float)vlo[ix] * INV_LO) * mk;
    }
    if (sub == 0) sbuf[d] = sum;
    __syncthreads();
    if (sub == 1) partial[(size_t)blockIdx.x * 128 + d] = sbuf[d] + sum;
}

// ---- pool stage 2: combine chunks, mean, dense ----
__global__ __launch_bounds__(128) void pool2_kernel(
    const float* __restrict__ partial, const int* __restrict__ node_types,
    const float* __restrict__ dense_w, const float* __restrict__ dense_b,
    float* __restrict__ out)
{
    __shared__ float s_part[2], s_cnt[2];
    const int b = blockIdx.x;
    const int d = threadIdx.x;
    float sum = 0.f;
    #pragma unroll
    for (int c = 0; c < 8; ++c) sum += partial[(size_t)(b * 8 + c) * 128 + d];
    float cnt = 0.f;
    #pragma unroll
    for (int i = 0; i < 4; ++i)
        cnt += (node_types[b * NN + d + i * 128] >= 0) ? 1.f : 0.f;
    #pragma unroll
    for (int off = 32; off > 0; off >>= 1) cnt += __shfl_xor(cnt, off);
    if ((d & 63) == 0) s_cnt[d >> 6] = cnt;
    __syncthreads();
    float tcnt = s_cnt[0] + s_cnt[1];
    float pv = (sum / tcnt) * dense_w[d];
    #pragma unroll
    for (int off = 32; off > 0; off >>= 1) pv += __shfl_down(pv, off);
    if ((d & 63) == 0) s_part[d >> 6] = pv;
    __syncthreads();
    if (d == 0) out[b] = s_part[0] + s_part[1] + dense_b[0];
}

extern "C" void kernel_launch(void* const* d_in, const int* in_sizes, int n_in,
                              void* d_out, int out_size, void* d_ws, size_t ws_size,
                              hipStream_t stream) {
    const int*   node_types    = (const int*)d_in[0];
    const int*   neighbor_list = (const int*)d_in[1];
    const int*   edge_types    = (const int*)d_in[2];
    const float* slot_types    = (const float*)d_in[3];
    const float* node_w        = (const float*)d_in[4];
    const float* edge_w        = (const float*)d_in[5];
    const float* wf            = (const float*)d_in[6];
    const float* bfv           = (const float*)d_in[7];
    const float* wsg           = (const float*)d_in[8];
    const float* bsv           = (const float*)d_in[9];
    const float* bn_gamma      = (const float*)d_in[10];
    const float* bn_beta       = (const float*)d_in[11];
    const float* bn_mean       = (const float*)d_in[12];
    const float* bn_var        = (const float*)d_in[13];
    const float* dense_w       = (const float*)d_in[14];
    const float* dense_b       = (const float*)d_in[15];
    float* out = (float*)d_out;

    float* wsf = (float*)d_ws;
    float* Ppk = wsf;                              // 8,388,608 f32
    float* Spk = wsf + 8388608;                    // 8,388,608 f32
    float* EWp = wsf + 2 * 8388608;                // 3*1001*256 = 768,768 f32
    float* pp  = EWp + 768768;                     // 65,536 f32 pool partials
    f16* f16b  = (f16*)(pp + 65536);
    f16* vhiA  = f16b;                             // 4,194,304 f16
    f16* vloA  = vhiA + 4194304;                   // 4,194,304 f16
    f16* Wc_hi = vloA + 4194304;                   // 196,608 f16
    f16* Wc_lo = Wc_hi + 196608;                   // 196,608 f16

    prep_kernel<<<768, 256, 0, stream>>>(wf, wsg, Wc_hi, Wc_lo);
    ew_kernel<<<NCONV * 32, 256, 0, stream>>>(edge_w, wf, wsg, EWp);
    embed_kernel<<<(NB * NN * ND) / 256, 256, 0, stream>>>(node_types, slot_types, node_w, vhiA, vloA);

    for (int c = 0; c < NCONV; ++c) {
        psgemm_kernel<<<2048, 256, 0, stream>>>(
            vhiA, vloA, Wc_hi + (size_t)c * 65536, Wc_lo + (size_t)c * 65536,
            bfv + c * ND, bsv + c * ND, Ppk, Spk);
        edge_epilogue_kernel<<<(NB * NN) / 2, 256, 0, stream>>>(
            vhiA, vloA, neighbor_list, edge_types,
            Ppk, Spk, EWp + (size_t)c * (VOCAB + 1) * 256,
            bn_gamma + c * ND, bn_beta + c * ND, bn_mean + c * ND, bn_var + c * ND);
    }

    pool1_kernel<<<NB * 8, 256, 0, stream>>>(vhiA, vloA, node_types, pp);
    pool2_kernel<<<NB, 128, 0, stream>>>(pp, node_types, dense_w, dense_b, out);
}

// Round 8
// 267.928 us; speedup vs baseline: 9.0896x; 1.0794x over previous
//
#include <hip/hip_runtime.h>

#define NB 64
#define NN 512
#define NL 12
#define ND 128
#define NZ 384
#define NCONV 3
#define VOCAB 1000
#define BN_EPS 1e-3f
#define LO_SCALE 2048.0f
#define INV_LO (1.0f/2048.0f)
#define SCF (-1.4426950408889634f)   // -log2(e): f-part scale
#define SCS ( 2.8853900817779268f)   //  2*log2(e): s-part scale

typedef _Float16 f16;
using half8 = __attribute__((ext_vector_type(8))) _Float16;
using floatx16 = __attribute__((ext_vector_type(16))) float;

__device__ __forceinline__ floatx16 mfma32(half8 a, half8 b, floatx16 c) {
    return __builtin_amdgcn_mfma_f32_32x32x16_f16(a, b, c, 0, 0, 0);
}
__device__ __forceinline__ void split1(float x, f16& h, f16& l) {
    h = (f16)x; l = (f16)((x - (float)h) * LO_SCALE);
}

// ---- prep: concatenated weight, k-chunk-major, f16 hi/lo ----
__global__ __launch_bounds__(256) void prep_kernel(
    const float* __restrict__ wf, const float* __restrict__ wsg,
    f16* __restrict__ Wc_hi, f16* __restrict__ Wc_lo)
{
    int id = blockIdx.x * 256 + threadIdx.x;   // 196608
    int c = id >> 16;
    int rem = id & 65535;
    int col = rem >> 7, k = rem & 127;
    int part = col >> 7;
    int d = col & 127;
    int z = (part < 2) ? (128 + k) : k;
    const float* W = (part & 1) ? wsg : wf;
    float wv = W[((size_t)c * NZ + z) * ND + d];
    f16 h, l; split1(wv, h, l);
    size_t dst = (size_t)c * 65536 + (size_t)(k >> 3) * 4096 + col * 8 + (k & 7);
    Wc_hi[dst] = h; Wc_lo[dst] = l;
}

// ---- EWp[c][type][ds] = float4{f(ds)*SCF, s(ds)*SCS, f(ds+64)*SCF, s(ds+64)*SCS} ----
// row VOCAB is all-zero (pad row)
__global__ __launch_bounds__(256) void ew_kernel(
    const float* __restrict__ edge_w, const float* __restrict__ wf,
    const float* __restrict__ wsg, float* __restrict__ EWp)
{
    __shared__ float se[32][128];
    const int c = blockIdx.x >> 5;
    const int tyg = (blockIdx.x & 31) * 32;
    const int tid = threadIdx.x;
    for (int i = tid; i < 4096; i += 256) {
        int ty = i >> 7, k = i & 127;
        int tyv = tyg + ty;
        se[ty][k] = (tyv < VOCAB) ? edge_w[(size_t)tyv * ND + k] : 0.f;
    }
    __syncthreads();
    const int h = tid >> 7, col = tid & 127;
    const float* W = h ? wsg : wf;
    const float sc = h ? SCS : SCF;
    float acc[32];
    #pragma unroll
    for (int ty = 0; ty < 32; ++ty) acc[ty] = 0.f;
    #pragma unroll 4
    for (int k = 0; k < 128; ++k) {
        float wv = W[((size_t)c * NZ + 256 + k) * ND + col];
        #pragma unroll
        for (int ty = 0; ty < 32; ++ty) acc[ty] = fmaf(se[ty][k], wv, acc[ty]);
    }
    #pragma unroll
    for (int ty = 0; ty < 32; ++ty) {
        int tyv = tyg + ty;
        if (tyv <= VOCAB)
            EWp[((size_t)c * (VOCAB + 1) + tyv) * 256 + (col & 63) * 4 + (col >> 6) * 2 + h] = acc[ty] * sc;
    }
}

// ---- embed: v = node_w[type]*m + slot -> hi/lo split ----
__global__ __launch_bounds__(256) void embed_kernel(
    const int* __restrict__ node_types, const float* __restrict__ slot_types,
    const float* __restrict__ node_w, f16* __restrict__ vhi, f16* __restrict__ vlo)
{
    int i = blockIdx.x * 256 + threadIdx.x;
    int bn = i >> 7, d = i & 127;
    int ty = node_types[bn];
    float m = ty >= 0 ? 1.f : 0.f;
    int idx = ty >= 0 ? ty : 0;
    float v = node_w[(size_t)idx * ND + d] * m + slot_types[i];
    f16 h, l; split1(v, h, l);
    vhi[i] = h; vlo[i] = l;
}

// ---- PS-GEMM -> Ppk/Spk in float4-paired layout [node][ds]{f,s,f+64,s+64} ----
__global__ __launch_bounds__(256, 3) void psgemm_kernel(
    const f16* __restrict__ vhi, const f16* __restrict__ vlo,
    const f16* __restrict__ Wc_hi, const f16* __restrict__ Wc_lo,  // pre-offset by conv
    const float* __restrict__ bfv, const float* __restrict__ bsv,  // pre-offset by conv
    float* __restrict__ Ppk, float* __restrict__ Spk)
{
    __shared__ __align__(16) char sA[16384];   // hi 32x256B @0, lo @8192 (XOR-swizzled)
    const int hw = blockIdx.x;
    const int xcd = hw & 7;
    const int q = hw >> 3;            // [0,256): 8 local batches x 2 halves x 16 groups
    const int bl = q >> 5;
    const int r = q & 31;
    const int half = r >> 4;
    const int xloc = r & 15;
    const int batch = bl * 8 + xcd;
    const int node0 = batch * NN + xloc * 32;

    const int tid = threadIdx.x;
    const int lane = tid & 63, w = tid >> 6;
    const int l31 = lane & 31, l32 = lane >> 5;

    #pragma unroll
    for (int it = 0; it < 2; ++it) {
        int slot = it * 256 + tid;
        int rr = slot >> 4, cc = slot & 15;
        int cs = cc ^ (rr & 15);
        size_t src = (size_t)(node0 + rr) * ND + cs * 8;
        *(half8*)(sA + rr * 256 + cc * 16) = *(const half8*)(vhi + src);
        *(half8*)(sA + 8192 + rr * 256 + cc * 16) = *(const half8*)(vlo + src);
    }
    __syncthreads();

    const int dcol = w * 32 + l31;
    const int col0 = half * 256 + dcol;     // f-part column
    const int col1 = col0 + 128;            // s-part column

    floatx16 a00 = {}, a10 = {}, a01 = {}, a11 = {};

    int ch0 = l32;
    half8 b0h = *(const half8*)(Wc_hi + (size_t)ch0 * 4096 + col0 * 8);
    half8 b0l = *(const half8*)(Wc_lo + (size_t)ch0 * 4096 + col0 * 8);
    half8 b1h = *(const half8*)(Wc_hi + (size_t)ch0 * 4096 + col1 * 8);
    half8 b1l = *(const half8*)(Wc_lo + (size_t)ch0 * 4096 + col1 * 8);

    #pragma unroll
    for (int ks = 0; ks < 8; ++ks) {
        half8 n0h, n0l, n1h, n1l;
        if (ks < 7) {
            int nch = (ks + 1) * 2 + l32;
            n0h = *(const half8*)(Wc_hi + (size_t)nch * 4096 + col0 * 8);
            n0l = *(const half8*)(Wc_lo + (size_t)nch * 4096 + col0 * 8);
            n1h = *(const half8*)(Wc_hi + (size_t)nch * 4096 + col1 * 8);
            n1l = *(const half8*)(Wc_lo + (size_t)nch * 4096 + col1 * 8);
        }
        int qq = (((ks * 2 + l32) ^ (l31 & 15)) << 4);
        half8 ah = *(const half8*)(sA + l31 * 256 + qq);
        half8 al = *(const half8*)(sA + 8192 + l31 * 256 + qq);
        a00 = mfma32(ah, b0h, a00);
        a10 = mfma32(ah, b0l, a10);
        a10 = mfma32(al, b0h, a10);
        a01 = mfma32(ah, b1h, a01);
        a11 = mfma32(ah, b1l, a11);
        a11 = mfma32(al, b1h, a11);
        b0h = n0h; b0l = n0l; b1h = n1h; b1l = n1l;
    }

    float bx = 0.f, by = 0.f;
    if (half) { bx = bfv[dcol]; by = bsv[dcol]; }
    float* outp = half ? Spk : Ppk;
    const int dsub = (dcol & 63) * 4 + (dcol >> 6) * 2;
    #pragma unroll
    for (int rr = 0; rr < 16; ++rr) {
        int orow = (rr & 3) + 8 * (rr >> 2) + 4 * l32;
        float2 v2 = { (a00[rr] + a10[rr] * INV_LO + bx) * SCF,
                      (a01[rr] + a11[rr] * INV_LO + by) * SCS };
        *(float2*)(outp + (size_t)(node0 + orow) * 256 + dsub) = v2;
    }
}

// ---- edge epilogue: wave = node; float4 gathers; no LDS, no syncthreads ----
__global__ __launch_bounds__(256, 2) void edge_epilogue_kernel(
    f16* __restrict__ vhi, f16* __restrict__ vlo,
    const int* __restrict__ neighbor_list, const int* __restrict__ edge_types,
    const float* __restrict__ Ppk, const float* __restrict__ Spk,
    const float* __restrict__ EWp,
    const float* __restrict__ bn_gamma, const float* __restrict__ bn_beta,
    const float* __restrict__ bn_mean, const float* __restrict__ bn_var)
{
    // decode: batch b on XCD b%8; 128 node-quads per batch
    const int hw = blockIdx.x;
    const int xcd = hw & 7;
    const int q = hw >> 3;               // [0,1024): 8 local batches x 128 quads
    const int b = (q >> 7) * 8 + xcd;
    const int j = q & 127;
    const int node0 = b * NN + j * 4;

    const int tid = threadIdx.x;
    const int w = tid >> 6, ds = tid & 63;
    const int node = node0 + w;
    const int bbase = b * NN;

    // lanes 0..11 hold this node's neighbor/edge indices
    int nlv = -1, etv = -1;
    if (ds < NL) {
        nlv = neighbor_list[node * NL + ds];
        etv = edge_types[node * NL + ds];
    }
    unsigned long long bm = __ballot(nlv >= 0);   // bits 0..11 = neighbor-valid

    // issue ALL gathers up front: 1 S + 12 P + 12 EW float4 loads (SGPR bases)
    float4 sp4 = *(const float4*)(Spk + (size_t)node * 256 + ds * 4);
    float4 p4[NL], e4[NL];
    #pragma unroll
    for (int l = 0; l < NL; ++l) {
        int nl_l = __builtin_amdgcn_readlane(nlv, l);
        int et_l = __builtin_amdgcn_readlane(etv, l);
        int ns = (nl_l >= 0) ? (bbase + nl_l) : node;   // safe row
        int es = (et_l >= 0) ? et_l : VOCAB;            // zero pad row
        p4[l] = *(const float4*)(Ppk + (size_t)ns * 256 + ds * 4);
        e4[l] = *(const float4*)(EWp + (size_t)es * 256 + ds * 4);
    }

    float sum0 = 0.f, sum1 = 0.f;
    #pragma unroll
    for (int l = 0; l < NL; ++l) {
        float m = ((bm >> l) & 1) ? 1.f : 0.f;          // wave-uniform
        float ax = p4[l].x + sp4.x + e4[l].x;           // pf ch0 (* -log2e)
        float ay = p4[l].y + sp4.y + e4[l].y;           // ps ch0 (* 2log2e)
        float az = p4[l].z + sp4.z + e4[l].z;           // pf ch1
        float aw = p4[l].w + sp4.w + e4[l].w;           // ps ch1
        float u0 = __builtin_amdgcn_exp2f(fminf(ax, 60.f));
        float w0 = __builtin_amdgcn_exp2f(fminf(ay, 60.f));
        float u1 = __builtin_amdgcn_exp2f(fminf(az, 60.f));
        float w1 = __builtin_amdgcn_exp2f(fminf(aw, 60.f));
        float r0 = __builtin_amdgcn_rcpf(fmaf(u0, w0, 1.f + u0 + w0));
        float r1 = __builtin_amdgcn_rcpf(fmaf(u1, w1, 1.f + u1 + w1));
        sum0 = fmaf((w0 - 1.f) * r0, m, sum0);
        sum1 = fmaf((w1 - 1.f) * r1, m, sum1);
    }

    size_t i0 = (size_t)node * ND + ds;
    size_t i1 = i0 + 64;
    float x0 = (float)vhi[i0] + (float)vlo[i0] * INV_LO + sum0;
    float x1 = (float)vhi[i1] + (float)vlo[i1] * INV_LO + sum1;
    int valid = __all(fabsf(x0) > 1e-5f && fabsf(x1) > 1e-5f);  // wave = node

    float gm0 = bn_gamma[ds], be0 = bn_beta[ds], mu0 = bn_mean[ds];
    float gm1 = bn_gamma[ds + 64], be1 = bn_beta[ds + 64], mu1 = bn_mean[ds + 64];
    float rs0 = __builtin_amdgcn_rcpf(sqrtf(bn_var[ds] + BN_EPS));
    float rs1 = __builtin_amdgcn_rcpf(sqrtf(bn_var[ds + 64] + BN_EPS));
    float o0 = valid ? (gm0 * (x0 - mu0) * rs0 + be0) : 0.f;
    float o1 = valid ? (gm1 * (x1 - mu1) * rs1 + be1) : 0.f;
    f16 h, l2;
    split1(o0, h, l2); vhi[i0] = h; vlo[i0] = l2;
    split1(o1, h, l2); vhi[i1] = h; vlo[i1] = l2;
}

// ---- pool stage 1: partial masked sums over 64-node chunks ----
__global__ __launch_bounds__(256) void pool1_kernel(
    const f16* __restrict__ vhi, const f16* __restrict__ vlo,
    const int* __restrict__ node_types, float* __restrict__ partial)
{
    __shared__ float sbuf[128];
    const int b = blockIdx.x >> 3, chunk = blockIdx.x & 7;
    const int d = threadIdx.x & 127, sub = threadIdx.x >> 7;
    const int n0 = chunk * 64 + sub * 32;
    float sum = 0.f;
    #pragma unroll 4
    for (int i = 0; i < 32; ++i) {
        int n = n0 + i;
        int ty = node_types[b * NN + n];
        float mk = ty >= 0 ? 1.f : 0.f;
        size_t ix = ((size_t)(b * NN + n)) * ND + d;
        sum += ((float)vhi[ix] + (float)vlo[ix] * INV_LO) * mk;
    }
    if (sub == 0) sbuf[d] = sum;
    __syncthreads();
    if (sub == 1) partial[(size_t)blockIdx.x * 128 + d] = sbuf[d] + sum;
}

// ---- pool stage 2: combine chunks, mean, dense ----
__global__ __launch_bounds__(128) void pool2_kernel(
    const float* __restrict__ partial, const int* __restrict__ node_types,
    const float* __restrict__ dense_w, const float* __restrict__ dense_b,
    float* __restrict__ out)
{
    __shared__ float s_part[2], s_cnt[2];
    const int b = blockIdx.x;
    const int d = threadIdx.x;
    float sum = 0.f;
    #pragma unroll
    for (int c = 0; c < 8; ++c) sum += partial[(size_t)(b * 8 + c) * 128 + d];
    float cnt = 0.f;
    #pragma unroll
    for (int i = 0; i < 4; ++i)
        cnt += (node_types[b * NN + d + i * 128] >= 0) ? 1.f : 0.f;
    #pragma unroll
    for (int off = 32; off > 0; off >>= 1) cnt += __shfl_xor(cnt, off);
    if ((d & 63) == 0) s_cnt[d >> 6] = cnt;
    __syncthreads();
    float tcnt = s_cnt[0] + s_cnt[1];
    float pv = (sum / tcnt) * dense_w[d];
    #pragma unroll
    for (int off = 32; off > 0; off >>= 1) pv += __shfl_down(pv, off);
    if ((d & 63) == 0) s_part[d >> 6] = pv;
    __syncthreads();
    if (d == 0) out[b] = s_part[0] + s_part[1] + dense_b[0];
}

extern "C" void kernel_launch(void* const* d_in, const int* in_sizes, int n_in,
                              void* d_out, int out_size, void* d_ws, size_t ws_size,
                              hipStream_t stream) {
    const int*   node_types    = (const int*)d_in[0];
    const int*   neighbor_list = (const int*)d_in[1];
    const int*   edge_types    = (const int*)d_in[2];
    const float* slot_types    = (const float*)d_in[3];
    const float* node_w        = (const float*)d_in[4];
    const float* edge_w        = (const float*)d_in[5];
    const float* wf            = (const float*)d_in[6];
    const float* bfv           = (const float*)d_in[7];
    const float* wsg           = (const float*)d_in[8];
    const float* bsv           = (const float*)d_in[9];
    const float* bn_gamma      = (const float*)d_in[10];
    const float* bn_beta       = (const float*)d_in[11];
    const float* bn_mean       = (const float*)d_in[12];
    const float* bn_var        = (const float*)d_in[13];
    const float* dense_w       = (const float*)d_in[14];
    const float* dense_b       = (const float*)d_in[15];
    float* out = (float*)d_out;

    float* wsf = (float*)d_ws;
    float* Ppk = wsf;                              // 8,388,608 f32
    float* Spk = wsf + 8388608;                    // 8,388,608 f32
    float* EWp = wsf + 2 * 8388608;                // 3*1001*256 = 768,768 f32
    float* pp  = EWp + 768768;                     // 65,536 f32 pool partials
    f16* f16b  = (f16*)(pp + 65536);
    f16* vhiA  = f16b;                             // 4,194,304 f16
    f16* vloA  = vhiA + 4194304;                   // 4,194,304 f16
    f16* Wc_hi = vloA + 4194304;                   // 196,608 f16
    f16* Wc_lo = Wc_hi + 196608;                   // 196,608 f16

    prep_kernel<<<768, 256, 0, stream>>>(wf, wsg, Wc_hi, Wc_lo);
    ew_kernel<<<NCONV * 32, 256, 0, stream>>>(edge_w, wf, wsg, EWp);
    embed_kernel<<<(NB * NN * ND) / 256, 256, 0, stream>>>(node_types, slot_types, node_w, vhiA, vloA);

    for (int c = 0; c < NCONV; ++c) {
        psgemm_kernel<<<2048, 256, 0, stream>>>(
            vhiA, vloA, Wc_hi + (size_t)c * 65536, Wc_lo + (size_t)c * 65536,
            bfv + c * ND, bsv + c * ND, Ppk, Spk);
        edge_epilogue_kernel<<<8192, 256, 0, stream>>>(
            vhiA, vloA, neighbor_list, edge_types,
            Ppk, Spk, EWp + (size_t)c * (VOCAB + 1) * 256,
            bn_gamma + c * ND, bn_beta + c * ND, bn_mean + c * ND, bn_var + c * ND);
    }

    pool1_kernel<<<NB * 8, 256, 0, stream>>>(vhiA, vloA, node_types, pp);
    pool2_kernel<<<NB, 128, 0, stream>>>(pp, node_types, dense_w, dense_b, out);
}

// Round 9
// 247.739 us; speedup vs baseline: 9.8303x; 1.0815x over previous
//
#include <hip/hip_runtime.h>

#define NB 64
#define NN 512
#define NL 12
#define ND 128
#define NZ 384
#define NCONV 3
#define VOCAB 1000
#define BN_EPS 1e-3f
#define LO_SCALE 2048.0f
#define INV_LO (1.0f/2048.0f)
#define SCF (-1.4426950408889634f)   // -log2(e): f-part scale
#define SCS ( 2.8853900817779268f)   //  2*log2(e): s-part scale

typedef _Float16 f16;
using half8 = __attribute__((ext_vector_type(8))) _Float16;
using floatx16 = __attribute__((ext_vector_type(16))) float;

__device__ __forceinline__ floatx16 mfma32(half8 a, half8 b, floatx16 c) {
    return __builtin_amdgcn_mfma_f32_32x32x16_f16(a, b, c, 0, 0, 0);
}
__device__ __forceinline__ void split1(float x, f16& h, f16& l) {
    h = (f16)x; l = (f16)((x - (float)h) * LO_SCALE);
}

// ---- merged setup: prep (blocks 0..767), ew (768..863), embed (864..17247) ----
__global__ __launch_bounds__(256) void setup_kernel(
    const float* __restrict__ wf, const float* __restrict__ wsg,
    f16* __restrict__ Wc_hi, f16* __restrict__ Wc_lo,
    const float* __restrict__ edge_w, float* __restrict__ EWp,
    const int* __restrict__ node_types, const float* __restrict__ slot_types,
    const float* __restrict__ node_w, f16* __restrict__ vhi, f16* __restrict__ vlo)
{
    __shared__ float se[32][128];
    const int blk = blockIdx.x;
    const int tid = threadIdx.x;
    if (blk < 768) {
        // ---- prep: concatenated weight, k-chunk-major, f16 hi/lo ----
        int id = blk * 256 + tid;                  // 196608
        int c = id >> 16;
        int rem = id & 65535;
        int col = rem >> 7, k = rem & 127;
        int part = col >> 7;
        int d = col & 127;
        int z = (part < 2) ? (128 + k) : k;
        const float* W = (part & 1) ? wsg : wf;
        float wv = W[((size_t)c * NZ + z) * ND + d];
        f16 h, l; split1(wv, h, l);
        size_t dst = (size_t)c * 65536 + (size_t)(k >> 3) * 4096 + col * 8 + (k & 7);
        Wc_hi[dst] = h; Wc_lo[dst] = l;
    } else if (blk < 864) {
        // ---- ew: EWp[c][type][ds] = float4{f(ds)*SCF, s(ds)*SCS, f(ds+64)*SCF, s(ds+64)*SCS} ----
        const int bid = blk - 768;
        const int c = bid >> 5;
        const int tyg = (bid & 31) * 32;
        for (int i = tid; i < 4096; i += 256) {
            int ty = i >> 7, k = i & 127;
            int tyv = tyg + ty;
            se[ty][k] = (tyv < VOCAB) ? edge_w[(size_t)tyv * ND + k] : 0.f;
        }
        __syncthreads();
        const int h = tid >> 7, col = tid & 127;
        const float* W = h ? wsg : wf;
        const float sc = h ? SCS : SCF;
        float acc[32];
        #pragma unroll
        for (int ty = 0; ty < 32; ++ty) acc[ty] = 0.f;
        #pragma unroll 4
        for (int k = 0; k < 128; ++k) {
            float wv = W[((size_t)c * NZ + 256 + k) * ND + col];
            #pragma unroll
            for (int ty = 0; ty < 32; ++ty) acc[ty] = fmaf(se[ty][k], wv, acc[ty]);
        }
        #pragma unroll
        for (int ty = 0; ty < 32; ++ty) {
            int tyv = tyg + ty;
            if (tyv <= VOCAB)   // include zero pad row at index VOCAB
                EWp[((size_t)c * (VOCAB + 1) + tyv) * 256 + (col & 63) * 4 + (col >> 6) * 2 + h] = acc[ty] * sc;
        }
    } else {
        // ---- embed: v = node_w[type]*m + slot -> hi/lo split ----
        int i = (blk - 864) * 256 + tid;
        int bn = i >> 7, d = i & 127;
        int ty = node_types[bn];
        float m = ty >= 0 ? 1.f : 0.f;
        int idx = ty >= 0 ? ty : 0;
        float v = node_w[(size_t)idx * ND + d] * m + slot_types[i];
        f16 h, l; split1(v, h, l);
        vhi[i] = h; vlo[i] = l;
    }
}

// ---- PS-GEMM -> Ppk/Spk in float4-paired layout [node][ds]{f,s,f+64,s+64} ----
__global__ __launch_bounds__(256, 3) void psgemm_kernel(
    const f16* __restrict__ vhi, const f16* __restrict__ vlo,
    const f16* __restrict__ Wc_hi, const f16* __restrict__ Wc_lo,  // pre-offset by conv
    const float* __restrict__ bfv, const float* __restrict__ bsv,  // pre-offset by conv
    float* __restrict__ Ppk, float* __restrict__ Spk)
{
    __shared__ __align__(16) char sA[16384];   // hi 32x256B @0, lo @8192 (XOR-swizzled)
    const int hw = blockIdx.x;
    const int xcd = hw & 7;
    const int q = hw >> 3;            // [0,256): 8 local batches x 2 halves x 16 groups
    const int bl = q >> 5;
    const int r = q & 31;
    const int half = r >> 4;
    const int xloc = r & 15;
    const int batch = bl * 8 + xcd;
    const int node0 = batch * NN + xloc * 32;

    const int tid = threadIdx.x;
    const int lane = tid & 63, w = tid >> 6;
    const int l31 = lane & 31, l32 = lane >> 5;

    #pragma unroll
    for (int it = 0; it < 2; ++it) {
        int slot = it * 256 + tid;
        int rr = slot >> 4, cc = slot & 15;
        int cs = cc ^ (rr & 15);
        size_t src = (size_t)(node0 + rr) * ND + cs * 8;
        *(half8*)(sA + rr * 256 + cc * 16) = *(const half8*)(vhi + src);
        *(half8*)(sA + 8192 + rr * 256 + cc * 16) = *(const half8*)(vlo + src);
    }
    __syncthreads();

    const int dcol = w * 32 + l31;
    const int col0 = half * 256 + dcol;     // f-part column
    const int col1 = col0 + 128;            // s-part column

    floatx16 a00 = {}, a10 = {}, a01 = {}, a11 = {};

    int ch0 = l32;
    half8 b0h = *(const half8*)(Wc_hi + (size_t)ch0 * 4096 + col0 * 8);
    half8 b0l = *(const half8*)(Wc_lo + (size_t)ch0 * 4096 + col0 * 8);
    half8 b1h = *(const half8*)(Wc_hi + (size_t)ch0 * 4096 + col1 * 8);
    half8 b1l = *(const half8*)(Wc_lo + (size_t)ch0 * 4096 + col1 * 8);

    #pragma unroll
    for (int ks = 0; ks < 8; ++ks) {
        half8 n0h, n0l, n1h, n1l;
        if (ks < 7) {
            int nch = (ks + 1) * 2 + l32;
            n0h = *(const half8*)(Wc_hi + (size_t)nch * 4096 + col0 * 8);
            n0l = *(const half8*)(Wc_lo + (size_t)nch * 4096 + col0 * 8);
            n1h = *(const half8*)(Wc_hi + (size_t)nch * 4096 + col1 * 8);
            n1l = *(const half8*)(Wc_lo + (size_t)nch * 4096 + col1 * 8);
        }
        int qq = (((ks * 2 + l32) ^ (l31 & 15)) << 4);
        half8 ah = *(const half8*)(sA + l31 * 256 + qq);
        half8 al = *(const half8*)(sA + 8192 + l31 * 256 + qq);
        a00 = mfma32(ah, b0h, a00);
        a10 = mfma32(ah, b0l, a10);
        a10 = mfma32(al, b0h, a10);
        a01 = mfma32(ah, b1h, a01);
        a11 = mfma32(ah, b1l, a11);
        a11 = mfma32(al, b1h, a11);
        b0h = n0h; b0l = n0l; b1h = n1h; b1l = n1l;
    }

    float bx = 0.f, by = 0.f;
    if (half) { bx = bfv[dcol]; by = bsv[dcol]; }
    float* outp = half ? Spk : Ppk;
    const int dsub = (dcol & 63) * 4 + (dcol >> 6) * 2;
    #pragma unroll
    for (int rr = 0; rr < 16; ++rr) {
        int orow = (rr & 3) + 8 * (rr >> 2) + 4 * l32;
        float2 v2 = { (a00[rr] + a10[rr] * INV_LO + bx) * SCF,
                      (a01[rr] + a11[rr] * INV_LO + by) * SCS };
        *(float2*)(outp + (size_t)(node0 + orow) * 256 + dsub) = v2;
    }
}

// ---- edge epilogue: 2 waves per node (6 l's each); float4 gathers; LDS pair-reduce ----
__global__ __launch_bounds__(256, 4) void edge_epilogue_kernel(
    f16* __restrict__ vhi, f16* __restrict__ vlo,
    const int* __restrict__ neighbor_list, const int* __restrict__ edge_types,
    const float* __restrict__ Ppk, const float* __restrict__ Spk,
    const float* __restrict__ EWp,
    const float* __restrict__ bn_gamma, const float* __restrict__ bn_beta,
    const float* __restrict__ bn_mean, const float* __restrict__ bn_var)
{
    __shared__ float s_red[2][64][2];
    // decode: batch b on XCD b%8; 256 node-pairs per batch
    const int hw = blockIdx.x;               // [0,16384)
    const int xcd = hw & 7;
    const int q = hw >> 3;                   // [0,2048): 8 local batches x 256 pairs
    const int b = (q >> 8) * 8 + xcd;
    const int j = q & 255;
    const int node0 = b * NN + j * 2;

    const int tid = threadIdx.x;
    const int w = tid >> 6, ds = tid & 63;
    const int nl_ = w >> 1;                  // node within pair
    const int sub = w & 1;                   // l-half: [sub*6, sub*6+6)
    const int node = node0 + nl_;
    const int bbase = b * NN;

    // lanes 0..5 hold this wave's 6 neighbor/edge indices
    int nlv = -1, etv = -1;
    if (ds < 6) {
        nlv = neighbor_list[node * NL + sub * 6 + ds];
        etv = edge_types[node * NL + sub * 6 + ds];
    }
    unsigned long long bm = __ballot(nlv >= 0);   // bits 0..5

    // issue gathers: 1 S + 6 P + 6 EW float4 loads (SGPR bases)
    float4 sp4 = *(const float4*)(Spk + (size_t)node * 256 + ds * 4);
    float4 p4[6], e4[6];
    #pragma unroll
    for (int l = 0; l < 6; ++l) {
        int nl_l = __builtin_amdgcn_readlane(nlv, l);
        int et_l = __builtin_amdgcn_readlane(etv, l);
        int ns = (nl_l >= 0) ? (bbase + nl_l) : node;   // safe row
        int es = (et_l >= 0) ? et_l : VOCAB;            // zero pad row
        p4[l] = *(const float4*)(Ppk + (size_t)ns * 256 + ds * 4);
        e4[l] = *(const float4*)(EWp + (size_t)es * 256 + ds * 4);
    }

    float sum0 = 0.f, sum1 = 0.f;
    #pragma unroll
    for (int l = 0; l < 6; ++l) {
        float m = ((bm >> l) & 1) ? 1.f : 0.f;          // wave-uniform
        float ax = p4[l].x + sp4.x + e4[l].x;           // pf ch0 (* -log2e)
        float ay = p4[l].y + sp4.y + e4[l].y;           // ps ch0 (* 2log2e)
        float az = p4[l].z + sp4.z + e4[l].z;           // pf ch1
        float aw = p4[l].w + sp4.w + e4[l].w;           // ps ch1
        float u0 = __builtin_amdgcn_exp2f(fminf(ax, 60.f));
        float w0 = __builtin_amdgcn_exp2f(fminf(ay, 60.f));
        float u1 = __builtin_amdgcn_exp2f(fminf(az, 60.f));
        float w1 = __builtin_amdgcn_exp2f(fminf(aw, 60.f));
        float r0 = __builtin_amdgcn_rcpf(fmaf(u0, w0, 1.f + u0 + w0));
        float r1 = __builtin_amdgcn_rcpf(fmaf(u1, w1, 1.f + u1 + w1));
        sum0 = fmaf((w0 - 1.f) * r0, m, sum0);
        sum1 = fmaf((w1 - 1.f) * r1, m, sum1);
    }

    if (sub) { s_red[nl_][ds][0] = sum0; s_red[nl_][ds][1] = sum1; }
    __syncthreads();
    if (!sub) {
        sum0 += s_red[nl_][ds][0];
        sum1 += s_red[nl_][ds][1];
        size_t i0 = (size_t)node * ND + ds;
        size_t i1 = i0 + 64;
        float x0 = (float)vhi[i0] + (float)vlo[i0] * INV_LO + sum0;
        float x1 = (float)vhi[i1] + (float)vlo[i1] * INV_LO + sum1;
        int valid = __all(fabsf(x0) > 1e-5f && fabsf(x1) > 1e-5f);  // 128 ch in-wave

        float gm0 = bn_gamma[ds], be0 = bn_beta[ds], mu0 = bn_mean[ds];
        float gm1 = bn_gamma[ds + 64], be1 = bn_beta[ds + 64], mu1 = bn_mean[ds + 64];
        float rs0 = __builtin_amdgcn_rcpf(sqrtf(bn_var[ds] + BN_EPS));
        float rs1 = __builtin_amdgcn_rcpf(sqrtf(bn_var[ds + 64] + BN_EPS));
        float o0 = valid ? (gm0 * (x0 - mu0) * rs0 + be0) : 0.f;
        float o1 = valid ? (gm1 * (x1 - mu1) * rs1 + be1) : 0.f;
        f16 h, l2;
        split1(o0, h, l2); vhi[i0] = h; vlo[i0] = l2;
        split1(o1, h, l2); vhi[i1] = h; vlo[i1] = l2;
    }
}

// ---- pool stage 1: partial masked sums over 64-node chunks ----
__global__ __launch_bounds__(256) void pool1_kernel(
    const f16* __restrict__ vhi, const f16* __restrict__ vlo,
    const int* __restrict__ node_types, float* __restrict__ partial)
{
    __shared__ float sbuf[128];
    const int b = blockIdx.x >> 3, chunk = blockIdx.x & 7;
    const int d = threadIdx.x & 127, sub = threadIdx.x >> 7;
    const int n0 = chunk * 64 + sub * 32;
    float sum = 0.f;
    #pragma unroll 4
    for (int i = 0; i < 32; ++i) {
        int n = n0 + i;
        int ty = node_types[b * NN + n];
        float mk = ty >= 0 ? 1.f : 0.f;
        size_t ix = ((size_t)(b * NN + n)) * ND + d;
        sum += ((float)vhi[ix] + (float)vlo[ix] * INV_LO) * mk;
    }
    if (sub == 0) sbuf[d] = sum;
    __syncthreads();
    if (sub == 1) partial[(size_t)blockIdx.x * 128 + d] = sbuf[d] + sum;
}

// ---- pool stage 2: combine chunks, mean, dense ----
__global__ __launch_bounds__(128) void pool2_kernel(
    const float* __restrict__ partial, const int* __restrict__ node_types,
    const float* __restrict__ dense_w, const float* __restrict__ dense_b,
    float* __restrict__ out)
{
    __shared__ float s_part[2], s_cnt[2];
    const int b = blockIdx.x;
    const int d = threadIdx.x;
    float sum = 0.f;
    #pragma unroll
    for (int c = 0; c < 8; ++c) sum += partial[(size_t)(b * 8 + c) * 128 + d];
    float cnt = 0.f;
    #pragma unroll
    for (int i = 0; i < 4; ++i)
        cnt += (node_types[b * NN + d + i * 128] >= 0) ? 1.f : 0.f;
    #pragma unroll
    for (int off = 32; off > 0; off >>= 1) cnt += __shfl_xor(cnt, off);
    if ((d & 63) == 0) s_cnt[d >> 6] = cnt;
    __syncthreads();
    float tcnt = s_cnt[0] + s_cnt[1];
    float pv = (sum / tcnt) * dense_w[d];
    #pragma unroll
    for (int off = 32; off > 0; off >>= 1) pv += __shfl_down(pv, off);
    if ((d & 63) == 0) s_part[d >> 6] = pv;
    __syncthreads();
    if (d == 0) out[b] = s_part[0] + s_part[1] + dense_b[0];
}

extern "C" void kernel_launch(void* const* d_in, const int* in_sizes, int n_in,
                              void* d_out, int out_size, void* d_ws, size_t ws_size,
                              hipStream_t stream) {
    const int*   node_types    = (const int*)d_in[0];
    const int*   neighbor_list = (const int*)d_in[1];
    const int*   edge_types    = (const int*)d_in[2];
    const float* slot_types    = (const float*)d_in[3];
    const float* node_w        = (const float*)d_in[4];
    const float* edge_w        = (const float*)d_in[5];
    const float* wf            = (const float*)d_in[6];
    const float* bfv           = (const float*)d_in[7];
    const float* wsg           = (const float*)d_in[8];
    const float* bsv           = (const float*)d_in[9];
    const float* bn_gamma      = (const float*)d_in[10];
    const float* bn_beta       = (const float*)d_in[11];
    const float* bn_mean       = (const float*)d_in[12];
    const float* bn_var        = (const float*)d_in[13];
    const float* dense_w       = (const float*)d_in[14];
    const float* dense_b       = (const float*)d_in[15];
    float* out = (float*)d_out;

    float* wsf = (float*)d_ws;
    float* Ppk = wsf;                              // 8,388,608 f32
    float* Spk = wsf + 8388608;                    // 8,388,608 f32
    float* EWp = wsf + 2 * 8388608;                // 3*1001*256 = 768,768 f32
    float* pp  = EWp + 768768;                     // 65,536 f32 pool partials
    f16* f16b  = (f16*)(pp + 65536);
    f16* vhiA  = f16b;                             // 4,194,304 f16
    f16* vloA  = vhiA + 4194304;                   // 4,194,304 f16
    f16* Wc_hi = vloA + 4194304;                   // 196,608 f16
    f16* Wc_lo = Wc_hi + 196608;                   // 196,608 f16

    setup_kernel<<<17248, 256, 0, stream>>>(
        wf, wsg, Wc_hi, Wc_lo, edge_w, EWp,
        node_types, slot_types, node_w, vhiA, vloA);

    for (int c = 0; c < NCONV; ++c) {
        psgemm_kernel<<<2048, 256, 0, stream>>>(
            vhiA, vloA, Wc_hi + (size_t)c * 65536, Wc_lo + (size_t)c * 65536,
            bfv + c * ND, bsv + c * ND, Ppk, Spk);
        edge_epilogue_kernel<<<16384, 256, 0, stream>>>(
            vhiA, vloA, neighbor_list, edge_types,
            Ppk, Spk, EWp + (size_t)c * (VOCAB + 1) * 256,
            bn_gamma + c * ND, bn_beta + c * ND, bn_mean + c * ND, bn_var + c * ND);
    }

    pool1_kernel<<<NB * 8, 256, 0, stream>>>(vhiA, vloA, node_types, pp);
    pool2_kernel<<<NB, 128, 0, stream>>>(pp, node_types, dense_w, dense_b, out);
}

// Round 10
// 245.700 us; speedup vs baseline: 9.9119x; 1.0083x over previous
//
#include <hip/hip_runtime.h>

#define NB 64
#define NN 512
#define NL 12
#define ND 128
#define NZ 384
#define NCONV 3
#define VOCAB 1000
#define BN_EPS 1e-3f
#define LO_SCALE 2048.0f
#define INV_LO (1.0f/2048.0f)
#define SCF (-1.4426950408889634f)   // -log2(e): f-part scale
#define SCS ( 2.8853900817779268f)   //  2*log2(e): s-part scale

typedef _Float16 f16;
using half8 = __attribute__((ext_vector_type(8))) _Float16;
using floatx16 = __attribute__((ext_vector_type(16))) float;

__device__ __forceinline__ floatx16 mfma32(half8 a, half8 b, floatx16 c) {
    return __builtin_amdgcn_mfma_f32_32x32x16_f16(a, b, c, 0, 0, 0);
}
__device__ __forceinline__ void split1(float x, f16& h, f16& l) {
    h = (f16)x; l = (f16)((x - (float)h) * LO_SCALE);
}

// ---- merged setup ----
// blocks [0,768): weight prep | [768,864): EW table | [864,866): BN pack | [866,17250): embed
__global__ __launch_bounds__(256) void setup_kernel(
    const float* __restrict__ wf, const float* __restrict__ wsg,
    f16* __restrict__ Wc_hi, f16* __restrict__ Wc_lo,
    const float* __restrict__ edge_w, float* __restrict__ EWp,
    const float* __restrict__ bn_gamma, const float* __restrict__ bn_beta,
    const float* __restrict__ bn_mean, const float* __restrict__ bn_var,
    float* __restrict__ bnp,
    const int* __restrict__ node_types, const float* __restrict__ slot_types,
    const float* __restrict__ node_w, float* __restrict__ vA)
{
    __shared__ float se[32][128];
    const int blk = blockIdx.x;
    const int tid = threadIdx.x;
    if (blk < 768) {
        // prep: concatenated weight, k-chunk-major, f16 hi/lo
        int id = blk * 256 + tid;                  // 196608
        int c = id >> 16;
        int rem = id & 65535;
        int col = rem >> 7, k = rem & 127;
        int part = col >> 7;
        int d = col & 127;
        int z = (part < 2) ? (128 + k) : k;
        const float* W = (part & 1) ? wsg : wf;
        float wv = W[((size_t)c * NZ + z) * ND + d];
        f16 h, l; split1(wv, h, l);
        size_t dst = (size_t)c * 65536 + (size_t)(k >> 3) * 4096 + col * 8 + (k & 7);
        Wc_hi[dst] = h; Wc_lo[dst] = l;
    } else if (blk < 864) {
        // ew: EWp[c][type][ds] = float4{f(ds)*SCF, s(ds)*SCS, f(ds+64)*SCF, s(ds+64)*SCS}
        const int bid = blk - 768;
        const int c = bid >> 5;
        const int tyg = (bid & 31) * 32;
        for (int i = tid; i < 4096; i += 256) {
            int ty = i >> 7, k = i & 127;
            int tyv = tyg + ty;
            se[ty][k] = (tyv < VOCAB) ? edge_w[(size_t)tyv * ND + k] : 0.f;
        }
        __syncthreads();
        const int h = tid >> 7, col = tid & 127;
        const float* W = h ? wsg : wf;
        const float sc = h ? SCS : SCF;
        float acc[32];
        #pragma unroll
        for (int ty = 0; ty < 32; ++ty) acc[ty] = 0.f;
        #pragma unroll 4
        for (int k = 0; k < 128; ++k) {
            float wv = W[((size_t)c * NZ + 256 + k) * ND + col];
            #pragma unroll
            for (int ty = 0; ty < 32; ++ty) acc[ty] = fmaf(se[ty][k], wv, acc[ty]);
        }
        #pragma unroll
        for (int ty = 0; ty < 32; ++ty) {
            int tyv = tyg + ty;
            if (tyv <= VOCAB)   // zero pad row at index VOCAB
                EWp[((size_t)c * (VOCAB + 1) + tyv) * 256 + (col & 63) * 4 + (col >> 6) * 2 + h] = acc[ty] * sc;
        }
    } else if (blk < 866) {
        // bn pack: bnp[c*128+j] = float4{gamma, beta, mean, rsqrt(var+eps)}
        int t = (blk - 864) * 256 + tid;           // [0,512)
        if (t < NCONV * ND) {
            int c = t >> 7, j = t & 127;
            float4 q;
            q.x = bn_gamma[c * ND + j];
            q.y = bn_beta[c * ND + j];
            q.z = bn_mean[c * ND + j];
            q.w = 1.f / sqrtf(bn_var[c * ND + j] + BN_EPS);
            *(float4*)(bnp + (size_t)t * 4) = q;
        }
    } else {
        // embed: v = node_w[type]*m + slot (f32)
        int i = (blk - 866) * 256 + tid;
        int bn = i >> 7, d = i & 127;
        int ty = node_types[bn];
        float m = ty >= 0 ? 1.f : 0.f;
        int idx = ty >= 0 ? ty : 0;
        vA[i] = node_w[(size_t)idx * ND + d] * m + slot_types[i];
    }
}

// ---- PS-GEMM -> Ppk/Spk float4-paired layout [node][ds]{f,s,f+64,s+64}; depth-2 B prefetch ----
__global__ __launch_bounds__(256, 3) void psgemm_kernel(
    const float* __restrict__ vA,
    const f16* __restrict__ Wc_hi, const f16* __restrict__ Wc_lo,  // pre-offset by conv
    const float* __restrict__ bfv, const float* __restrict__ bsv,  // pre-offset by conv
    float* __restrict__ Ppk, float* __restrict__ Spk)
{
    __shared__ __align__(16) char sA[16384];   // hi 32x256B @0, lo @8192 (XOR-swizzled)
    const int hw = blockIdx.x;
    const int xcd = hw & 7;
    const int q = hw >> 3;            // [0,256): 8 local batches x 2 halves x 16 groups
    const int bl = q >> 5;
    const int r = q & 31;
    const int half = r >> 4;
    const int xloc = r & 15;
    const int batch = bl * 8 + xcd;
    const int node0 = batch * NN + xloc * 32;

    const int tid = threadIdx.x;
    const int lane = tid & 63, w = tid >> 6;
    const int l31 = lane & 31, l32 = lane >> 5;

    #pragma unroll
    for (int it = 0; it < 2; ++it) {
        int slot = it * 256 + tid;
        int rr = slot >> 4, cc = slot & 15;
        int cs = cc ^ (rr & 15);
        const float* vp = vA + (size_t)(node0 + rr) * ND + cs * 8;
        float4 u0 = *(const float4*)vp;
        float4 u1 = *(const float4*)(vp + 4);
        float uu[8] = {u0.x, u0.y, u0.z, u0.w, u1.x, u1.y, u1.z, u1.w};
        half8 hh, ll;
        #pragma unroll
        for (int jj = 0; jj < 8; ++jj) {
            f16 h, l; split1(uu[jj], h, l);
            hh[jj] = h; ll[jj] = l;
        }
        *(half8*)(sA + rr * 256 + cc * 16) = hh;
        *(half8*)(sA + 8192 + rr * 256 + cc * 16) = ll;
    }
    __syncthreads();

    const int dcol = w * 32 + l31;
    const int col0 = half * 256 + dcol;     // f-part column
    const int col1 = col0 + 128;            // s-part column

    floatx16 a00 = {}, a10 = {}, a01 = {}, a11 = {};

    half8 B[3][4];
    #define LDB(dst, ks) { \
        size_t k0 = (size_t)((ks) * 2 + l32) * 4096; \
        (dst)[0] = *(const half8*)(Wc_hi + k0 + col0 * 8); \
        (dst)[1] = *(const half8*)(Wc_lo + k0 + col0 * 8); \
        (dst)[2] = *(const half8*)(Wc_hi + k0 + col1 * 8); \
        (dst)[3] = *(const half8*)(Wc_lo + k0 + col1 * 8); }
    LDB(B[0], 0)
    LDB(B[1], 1)

    #pragma unroll
    for (int ks = 0; ks < 8; ++ks) {
        if (ks < 6) LDB(B[(ks + 2) % 3], ks + 2)
        const half8* Bc = B[ks % 3];
        int qq = (((ks * 2 + l32) ^ (l31 & 15)) << 4);
        half8 ah = *(const half8*)(sA + l31 * 256 + qq);
        half8 al = *(const half8*)(sA + 8192 + l31 * 256 + qq);
        a00 = mfma32(ah, Bc[0], a00);
        a10 = mfma32(ah, Bc[1], a10);
        a10 = mfma32(al, Bc[0], a10);
        a01 = mfma32(ah, Bc[2], a01);
        a11 = mfma32(ah, Bc[3], a11);
        a11 = mfma32(al, Bc[2], a11);
    }
    #undef LDB

    float bx = 0.f, by = 0.f;
    if (half) { bx = bfv[dcol]; by = bsv[dcol]; }
    float* outp = half ? Spk : Ppk;
    const int dsub = (dcol & 63) * 4 + (dcol >> 6) * 2;
    #pragma unroll
    for (int rr = 0; rr < 16; ++rr) {
        int orow = (rr & 3) + 8 * (rr >> 2) + 4 * l32;
        float2 v2 = { (a00[rr] + a10[rr] * INV_LO + bx) * SCF,
                      (a01[rr] + a11[rr] * INV_LO + by) * SCS };
        *(float2*)(outp + (size_t)(node0 + orow) * 256 + dsub) = v2;
    }
}

// ---- edge epilogue: 2 waves/node (6 l each); all gathers fenced before compute ----
__global__ __launch_bounds__(256, 4) void edge_epilogue_kernel(
    float* __restrict__ vA,
    const int* __restrict__ neighbor_list, const int* __restrict__ edge_types,
    const float* __restrict__ Ppk, const float* __restrict__ Spk,
    const float* __restrict__ EWp, const float* __restrict__ bnp,
    const float* __restrict__ /*unused*/, const float* __restrict__ /*unused2*/)
{
    __shared__ float s_red[2][64][2];
    const int hw = blockIdx.x;               // [0,16384)
    const int xcd = hw & 7;
    const int q = hw >> 3;                   // [0,2048): 8 local batches x 256 pairs
    const int b = (q >> 8) * 8 + xcd;
    const int j = q & 255;
    const int node0 = b * NN + j * 2;

    const int tid = threadIdx.x;
    const int w = tid >> 6, ds = tid & 63;
    const int nl_ = w >> 1;                  // node within pair
    const int sub = w & 1;                   // l-half
    const int node = node0 + nl_;
    const int bbase = b * NN;

    int nlv = -1, etv = -1;
    if (ds < 6) {
        nlv = neighbor_list[node * NL + sub * 6 + ds];
        etv = edge_types[node * NL + sub * 6 + ds];
    }
    unsigned long long bm = __ballot(nlv >= 0);   // bits 0..5

    // issue gathers: 1 S + 6 P + 6 EW float4 (SGPR row bases) — fenced so none sink
    float4 sp4 = *(const float4*)(Spk + (size_t)node * 256 + ds * 4);
    float4 p4[6], e4[6];
    #pragma unroll
    for (int l = 0; l < 6; ++l) {
        int nl_l = __builtin_amdgcn_readlane(nlv, l);
        int et_l = __builtin_amdgcn_readlane(etv, l);
        int ns = (nl_l >= 0) ? (bbase + nl_l) : node;   // safe row
        int es = (et_l >= 0) ? et_l : VOCAB;            // zero pad row
        p4[l] = *(const float4*)(Ppk + (size_t)ns * 256 + ds * 4);
        e4[l] = *(const float4*)(EWp + (size_t)es * 256 + ds * 4);
    }
    __builtin_amdgcn_sched_barrier(0);

    float sum0 = 0.f, sum1 = 0.f;
    #pragma unroll
    for (int l = 0; l < 6; ++l) {
        float m = ((bm >> l) & 1) ? 1.f : 0.f;          // wave-uniform
        float ax = p4[l].x + sp4.x + e4[l].x;           // pf ch0 (* -log2e)
        float ay = p4[l].y + sp4.y + e4[l].y;           // ps ch0 (* 2log2e)
        float az = p4[l].z + sp4.z + e4[l].z;           // pf ch1
        float aw = p4[l].w + sp4.w + e4[l].w;           // ps ch1
        float u0 = __builtin_amdgcn_exp2f(fminf(ax, 60.f));
        float w0 = __builtin_amdgcn_exp2f(fminf(ay, 60.f));
        float u1 = __builtin_amdgcn_exp2f(fminf(az, 60.f));
        float w1 = __builtin_amdgcn_exp2f(fminf(aw, 60.f));
        float r0 = __builtin_amdgcn_rcpf(fmaf(u0, w0, 1.f + u0 + w0));
        float r1 = __builtin_amdgcn_rcpf(fmaf(u1, w1, 1.f + u1 + w1));
        sum0 = fmaf((w0 - 1.f) * r0, m, sum0);
        sum1 = fmaf((w1 - 1.f) * r1, m, sum1);
    }

    if (sub) { s_red[nl_][ds][0] = sum0; s_red[nl_][ds][1] = sum1; }
    __syncthreads();
    if (!sub) {
        sum0 += s_red[nl_][ds][0];
        sum1 += s_red[nl_][ds][1];
        size_t i0 = (size_t)node * ND + ds;
        size_t i1 = i0 + 64;
        float x0 = vA[i0] + sum0;
        float x1 = vA[i1] + sum1;
        int valid = __all(fabsf(x0) > 1e-5f && fabsf(x1) > 1e-5f);  // 128 ch in-wave
        float4 q0 = *(const float4*)(bnp + (size_t)ds * 4);
        float4 q1 = *(const float4*)(bnp + (size_t)(ds + 64) * 4);
        vA[i0] = valid ? (q0.x * (x0 - q0.z) * q0.w + q0.y) : 0.f;
        vA[i1] = valid ? (q1.x * (x1 - q1.z) * q1.w + q1.y) : 0.f;
    }
}

// ---- pool: one kernel; 64 blocks x 512 threads ----
__global__ __launch_bounds__(512) void pool_kernel(
    const float* __restrict__ vA, const int* __restrict__ node_types,
    const float* __restrict__ dense_w, const float* __restrict__ dense_b,
    float* __restrict__ out)
{
    __shared__ float s_sum[4][128];
    __shared__ float s_cnt[4];
    __shared__ float s_part[2];
    const int b = blockIdx.x;
    const int tid = threadIdx.x;
    const int d = tid & 127, chunk = tid >> 7;
    const int nbase = b * NN + chunk * 128;
    float sum = 0.f, cnt = 0.f;
    #pragma unroll 4
    for (int i = 0; i < 128; ++i) {
        int ty = node_types[nbase + i];
        float mk = ty >= 0 ? 1.f : 0.f;
        sum += vA[(size_t)(nbase + i) * ND + d] * mk;
        cnt += mk;
    }
    s_sum[chunk][d] = sum;
    if (d == 0) s_cnt[chunk] = cnt;
    __syncthreads();
    if (chunk == 0) {
        float tot = s_sum[0][d] + s_sum[1][d] + s_sum[2][d] + s_sum[3][d];
        float tcnt = s_cnt[0] + s_cnt[1] + s_cnt[2] + s_cnt[3];
        float pv = (tot / tcnt) * dense_w[d];
        #pragma unroll
        for (int off = 32; off > 0; off >>= 1) pv += __shfl_down(pv, off);
        if ((d & 63) == 0) s_part[d >> 6] = pv;
    }
    __syncthreads();
    if (tid == 0) out[b] = s_part[0] + s_part[1] + dense_b[0];
}

extern "C" void kernel_launch(void* const* d_in, const int* in_sizes, int n_in,
                              void* d_out, int out_size, void* d_ws, size_t ws_size,
                              hipStream_t stream) {
    const int*   node_types    = (const int*)d_in[0];
    const int*   neighbor_list = (const int*)d_in[1];
    const int*   edge_types    = (const int*)d_in[2];
    const float* slot_types    = (const float*)d_in[3];
    const float* node_w        = (const float*)d_in[4];
    const float* edge_w        = (const float*)d_in[5];
    const float* wf            = (const float*)d_in[6];
    const float* bfv           = (const float*)d_in[7];
    const float* wsg           = (const float*)d_in[8];
    const float* bsv           = (const float*)d_in[9];
    const float* bn_gamma      = (const float*)d_in[10];
    const float* bn_beta       = (const float*)d_in[11];
    const float* bn_mean       = (const float*)d_in[12];
    const float* bn_var        = (const float*)d_in[13];
    const float* dense_w       = (const float*)d_in[14];
    const float* dense_b       = (const float*)d_in[15];
    float* out = (float*)d_out;

    float* wsf = (float*)d_ws;
    float* Ppk = wsf;                              // 8,388,608 f32
    float* Spk = wsf + 8388608;                    // 8,388,608 f32
    float* EWp = wsf + 2 * 8388608;                // 3*1001*256 = 768,768 f32
    float* bnp = EWp + 768768;                     // 3*128*4 = 1,536 f32
    float* vA  = bnp + 1536;                       // 4,194,304 f32
    f16* Wc_hi = (f16*)(vA + 4194304);             // 196,608 f16
    f16* Wc_lo = Wc_hi + 196608;                   // 196,608 f16

    setup_kernel<<<17250, 256, 0, stream>>>(
        wf, wsg, Wc_hi, Wc_lo, edge_w, EWp,
        bn_gamma, bn_beta, bn_mean, bn_var, bnp,
        node_types, slot_types, node_w, vA);

    for (int c = 0; c < NCONV; ++c) {
        psgemm_kernel<<<2048, 256, 0, stream>>>(
            vA, Wc_hi + (size_t)c * 65536, Wc_lo + (size_t)c * 65536,
            bfv + c * ND, bsv + c * ND, Ppk, Spk);
        edge_epilogue_kernel<<<16384, 256, 0, stream>>>(
            vA, neighbor_list, edge_types,
            Ppk, Spk, EWp + (size_t)c * (VOCAB + 1) * 256,
            bnp + (size_t)c * 512, nullptr, nullptr);
    }

    pool_kernel<<<NB, 512, 0, stream>>>(vA, node_types, dense_w, dense_b, out);
}